// Round 1
// baseline (454.353 us; speedup 1.0000x reference)
//
#include <hip/hip_runtime.h>
#include <hip/hip_bf16.h>
#include <math.h>

typedef __bf16 bf16;
typedef __attribute__((ext_vector_type(8))) __bf16 bf16x8;
typedef __attribute__((ext_vector_type(4))) __bf16 bf16x4;
typedef __attribute__((ext_vector_type(4))) float f32x4;

#define B_  16
#define S_  512
#define H_  768
#define NH_ 12
#define HD_ 64
#define A_  (B_*S_)   // 8192 token rows

// async global->LDS, 16B per lane; LDS dest = wave-uniform base + lane*16
__device__ __forceinline__ void gload_lds16(const void* g, void* l) {
  __builtin_amdgcn_global_load_lds((const __attribute__((address_space(1))) void*)g,
                                   (__attribute__((address_space(3))) void*)l, 16, 0, 0);
}

// ---------------- generic 128x128 bf16 MFMA GEMM: C = A @ Bt^T (+bias, epilogues) ----
// EPI 0: QKV scatter -> q[B,NH,S,HD], k[B,NH,S,HD], vt[B,NH,HD,S] (all bf16)
// EPI 1: outF = acc + bias + res   (fp32)
// EPI 2: outB = gelu(acc + bias)   (bf16)
template<int EPI>
__global__ __launch_bounds__(256) void k_gemm(
    const bf16* __restrict__ Amat, const bf16* __restrict__ Bt,
    const float* __restrict__ bias, const float* __restrict__ res,
    float* __restrict__ outF, bf16* __restrict__ outB,
    bf16* __restrict__ outQ, bf16* __restrict__ outK, bf16* __restrict__ outVT,
    int M, int N, int K)
{
  __shared__ __align__(16) bf16 As[128*32];
  __shared__ __align__(16) bf16 Bs[128*32];
  const int tid = threadIdx.x;
  const int w = tid >> 6, l = tid & 63;
  const int lr = l & 15, lg = l >> 4;
  const int row0 = blockIdx.y * 128, col0 = blockIdx.x * 128;
  const int wm = w >> 1, wn = w & 1;

  f32x4 acc[4][4] = {};

  for (int kk = 0; kk < K; kk += 32) {
#pragma unroll
    for (int j = 0; j < 2; ++j) {
      const int c = (w*2 + j)*64 + l;       // chunk id 0..511 (16B each)
      const int r = c >> 2;                 // tile row 0..127
      const int cc = (c & 3) * 8;           // col element offset
      gload_lds16(Amat + (size_t)(row0 + r)*K + kk + cc, As + (w*2 + j)*512);
      gload_lds16(Bt   + (size_t)(col0 + r)*K + kk + cc, Bs + (w*2 + j)*512);
    }
    __syncthreads();
    bf16x8 af[4], bfr[4];
    const bf16* Ab = As + (wm*64 + lr)*32 + lg*8;
    const bf16* Bb = Bs + (wn*64 + lr)*32 + lg*8;
#pragma unroll
    for (int t = 0; t < 4; ++t) {
      af[t]  = *(const bf16x8*)(Ab + t*512);   // +16 rows
      bfr[t] = *(const bf16x8*)(Bb + t*512);
    }
#pragma unroll
    for (int mt = 0; mt < 4; ++mt)
#pragma unroll
      for (int nt = 0; nt < 4; ++nt)
        acc[mt][nt] = __builtin_amdgcn_mfma_f32_16x16x32_bf16(af[mt], bfr[nt], acc[mt][nt], 0, 0, 0);
    __syncthreads();
  }

#pragma unroll
  for (int mt = 0; mt < 4; ++mt) {
#pragma unroll
    for (int nt = 0; nt < 4; ++nt) {
#pragma unroll
      for (int i = 0; i < 4; ++i) {
        const int row = row0 + wm*64 + mt*16 + lg*4 + i;
        const int col = col0 + wn*64 + nt*16 + lr;
        float v = acc[mt][nt][i] + bias[col];
        if constexpr (EPI == 1) {
          v += res[(size_t)row*N + col];
          outF[(size_t)row*N + col] = v;
        } else if constexpr (EPI == 2) {
          v = 0.5f * v * (1.0f + erff(v * 0.7071067811865475f));
          outB[(size_t)row*N + col] = (bf16)v;
        } else {
          const int b = row >> 9, s = row & 511;
          const int which = col / H_;
          const int hcol = col - which * H_;
          const int h = hcol >> 6, d = hcol & 63;
          const size_t bh = (size_t)b * NH_ + h;
          if (which == 0)      outQ[(bh*S_ + s)*HD_ + d] = (bf16)v;
          else if (which == 1) outK[(bh*S_ + s)*HD_ + d] = (bf16)v;
          else                 outVT[(bh*HD_ + d)*S_ + s] = (bf16)v;
        }
      }
    }
  }
}

// ---------------- attention scores + softmax: P[bh, q, :] into d_out ----------------
__global__ __launch_bounds__(256) void k_attn_scores(
    const bf16* __restrict__ Q, const bf16* __restrict__ Km,
    const unsigned char* __restrict__ mask, float* __restrict__ P)
{
  __shared__ __align__(16) bf16 Ks[512*64];  // full K for this head, 64KB
  __shared__ __align__(16) bf16 Qs[64*64];   // 64 q rows, 8KB
  const int tid = threadIdx.x, w = tid >> 6, l = tid & 63;
  const int lr = l & 15, lg = l >> 4;
  const int bh = blockIdx.x, qt = blockIdx.y;
  const int b = bh / NH_;
  const bf16* Kg = Km + (size_t)bh * S_ * HD_;
  const bf16* Qg = Q  + (size_t)bh * S_ * HD_ + (size_t)qt * 64 * HD_;
#pragma unroll
  for (int rnd = 0; rnd < 16; ++rnd)
    gload_lds16(Kg + ((size_t)rnd*256 + w*64 + l)*8, Ks + (rnd*4 + w)*512);
#pragma unroll
  for (int rnd = 0; rnd < 2; ++rnd)
    gload_lds16(Qg + ((size_t)rnd*256 + w*64 + l)*8, Qs + (rnd*4 + w)*512);
  __syncthreads();

  bf16x8 qf0 = *(const bf16x8*)(Qs + (w*16 + lr)*64 + lg*8);
  bf16x8 qf1 = *(const bf16x8*)(Qs + (w*16 + lr)*64 + 32 + lg*8);
  f32x4 acc[32];
#pragma unroll
  for (int ct = 0; ct < 32; ++ct) acc[ct] = f32x4{0.f,0.f,0.f,0.f};
#pragma unroll
  for (int ct = 0; ct < 32; ++ct) {
    bf16x8 k0 = *(const bf16x8*)(Ks + (ct*16 + lr)*64 + lg*8);
    bf16x8 k1 = *(const bf16x8*)(Ks + (ct*16 + lr)*64 + 32 + lg*8);
    acc[ct] = __builtin_amdgcn_mfma_f32_16x16x32_bf16(qf0, k0, acc[ct], 0, 0, 0);
    acc[ct] = __builtin_amdgcn_mfma_f32_16x16x32_bf16(qf1, k1, acc[ct], 0, 0, 0);
  }
  const float scale = 0.125f;  // 1/sqrt(64)
  const unsigned char* mrow = mask + b * S_;
#pragma unroll
  for (int ct = 0; ct < 32; ++ct) {
    const bool mk = mrow[ct*16 + lr] != 0;
#pragma unroll
    for (int i = 0; i < 4; ++i)
      acc[ct][i] = mk ? -1e30f : acc[ct][i] * scale;
  }
  // softmax across the 512 cols of each row (row lives in the 16 lanes sharing lg)
#pragma unroll
  for (int i = 0; i < 4; ++i) {
    float m = -1e30f;
#pragma unroll
    for (int ct = 0; ct < 32; ++ct) m = fmaxf(m, acc[ct][i]);
#pragma unroll
    for (int d = 1; d < 16; d <<= 1) m = fmaxf(m, __shfl_xor(m, d));
    float s = 0.f;
#pragma unroll
    for (int ct = 0; ct < 32; ++ct) { float e = expf(acc[ct][i] - m); acc[ct][i] = e; s += e; }
#pragma unroll
    for (int d = 1; d < 16; d <<= 1) s += __shfl_xor(s, d);
    const float inv = 1.f / s;
    float* prow = P + ((size_t)bh*S_ + (size_t)qt*64 + w*16 + lg*4 + i) * S_;
#pragma unroll
    for (int ct = 0; ct < 32; ++ct) prow[ct*16 + lr] = acc[ct][i] * inv;
  }
}

// ---------------- PV: attn_out[b,s,h*64+d] = P @ V ----------------------------------
__global__ __launch_bounds__(256) void k_attn_pv(
    const float* __restrict__ P, const bf16* __restrict__ VT, bf16* __restrict__ AO)
{
  __shared__ __align__(16) bf16 Vs[64*512];  // V^T for this head, 64KB
  __shared__ __align__(16) bf16 Ps[64*32];   // P chunk as bf16, 4KB
  const int tid = threadIdx.x, w = tid >> 6, l = tid & 63;
  const int lr = l & 15, lg = l >> 4;
  const int bh = blockIdx.x, qt = blockIdx.y;
  const int b = bh / NH_, h = bh % NH_;
  const bf16* Vg = VT + (size_t)bh * HD_ * S_;
#pragma unroll
  for (int rnd = 0; rnd < 16; ++rnd)
    gload_lds16(Vg + ((size_t)rnd*256 + w*64 + l)*8, Vs + (rnd*4 + w)*512);
  const float* Pg = P + ((size_t)bh*S_ + (size_t)qt*64) * S_;
  f32x4 acc[4] = {};
  const int pr = tid >> 2, pc = (tid & 3) * 8;
  for (int kk = 0; kk < 512; kk += 32) {
    __syncthreads();  // also drains VT staging on first iter; protects Ps reuse after
    float4 p0 = *(const float4*)(Pg + (size_t)pr*S_ + kk + pc);
    float4 p1 = *(const float4*)(Pg + (size_t)pr*S_ + kk + pc + 4);
    bf16x8 pb;
    pb[0]=(bf16)p0.x; pb[1]=(bf16)p0.y; pb[2]=(bf16)p0.z; pb[3]=(bf16)p0.w;
    pb[4]=(bf16)p1.x; pb[5]=(bf16)p1.y; pb[6]=(bf16)p1.z; pb[7]=(bf16)p1.w;
    *(bf16x8*)(Ps + pr*32 + pc) = pb;
    __syncthreads();
    bf16x8 pf = *(const bf16x8*)(Ps + (w*16 + lr)*32 + lg*8);
#pragma unroll
    for (int nt = 0; nt < 4; ++nt) {
      bf16x8 vf = *(const bf16x8*)(Vs + (nt*16 + lr)*512 + kk + lg*8);
      acc[nt] = __builtin_amdgcn_mfma_f32_16x16x32_bf16(pf, vf, acc[nt], 0, 0, 0);
    }
  }
#pragma unroll
  for (int nt = 0; nt < 4; ++nt)
#pragma unroll
    for (int i = 0; i < 4; ++i) {
      const int q = qt*64 + w*16 + lg*4 + i;
      AO[((size_t)(b*S_ + q))*H_ + h*HD_ + nt*16 + lr] = (bf16)acc[nt][i];
    }
}

// ---------------- LayerNorm over H=768, one row per block ---------------------------
__global__ __launch_bounds__(256) void k_layernorm(
    const float* __restrict__ X, const float* __restrict__ g, const float* __restrict__ bta,
    float* __restrict__ outF, bf16* __restrict__ outB)
{
  const int row = blockIdx.x;
  const int tid = threadIdx.x;
  const float* x = X + (size_t)row * H_;
  float v[3]; float s = 0.f, ss = 0.f;
#pragma unroll
  for (int j = 0; j < 3; ++j) { v[j] = x[tid + j*256]; s += v[j]; ss += v[j]*v[j]; }
#pragma unroll
  for (int d = 1; d < 64; d <<= 1) { s += __shfl_xor(s, d); ss += __shfl_xor(ss, d); }
  __shared__ float red[8];
  const int w = tid >> 6, l = tid & 63;
  if (l == 0) { red[w] = s; red[4 + w] = ss; }
  __syncthreads();
  s  = red[0] + red[1] + red[2] + red[3];
  ss = red[4] + red[5] + red[6] + red[7];
  const float mean = s * (1.f / H_);
  const float var  = ss * (1.f / H_) - mean * mean;
  const float inv  = rsqrtf(var + 1e-5f);
#pragma unroll
  for (int j = 0; j < 3; ++j) {
    const int c = tid + j*256;
    const float y = (v[j] - mean) * inv * g[c] + bta[c];
    if (outF) outF[(size_t)row*H_ + c] = y;
    if (outB) outB[(size_t)row*H_ + c] = (bf16)y;
  }
}

// ---------------- fp32 -> bf16 convert ----------------------------------------------
__global__ void k_f32_bf16(const float* __restrict__ in, bf16* __restrict__ out, int n) {
  const int i = (blockIdx.x * 256 + threadIdx.x) * 4;
  if (i < n) {
    const float4 vv = *(const float4*)(in + i);
    bf16x4 o; o[0]=(bf16)vv.x; o[1]=(bf16)vv.y; o[2]=(bf16)vv.z; o[3]=(bf16)vv.w;
    *(bf16x4*)(out + i) = o;
  }
}

extern "C" void kernel_launch(void* const* d_in, const int* in_sizes, int n_in,
                              void* d_out, int out_size, void* d_ws, size_t ws_size,
                              hipStream_t stream) {
  const float* x      = (const float*)d_in[0];
  const unsigned char* mask = (const unsigned char*)d_in[1];  // all-False in setup; zero bytes either way
  const float* w_qkv  = (const float*)d_in[2];
  const float* b_qkv  = (const float*)d_in[3];
  const float* w_out  = (const float*)d_in[4];
  const float* b_out  = (const float*)d_in[5];
  const float* w1     = (const float*)d_in[6];
  const float* b1     = (const float*)d_in[7];
  const float* w2     = (const float*)d_in[8];
  const float* b2     = (const float*)d_in[9];
  const float* ln1g   = (const float*)d_in[10];
  const float* ln1b   = (const float*)d_in[11];
  const float* ln2g   = (const float*)d_in[12];
  const float* ln2b   = (const float*)d_in[13];

  float* xout = (float*)d_out;                      // [8192, 768]
  float* P    = xout + (size_t)A_ * H_;             // [192, 512, 512] attn weights

  char* ws = (char*)d_ws;
  size_t off = 0;
  auto alloc = [&](size_t bytes) { char* p = ws + off; off += (bytes + 255) & ~255ull; return p; };

  bf16* xb   = (bf16*)alloc((size_t)A_*H_*2);          // x as bf16
  bf16* wqkv = (bf16*)alloc((size_t)3*H_*H_*2);
  bf16* wo   = (bf16*)alloc((size_t)H_*H_*2);
  bf16* w1b  = (bf16*)alloc((size_t)4*H_*H_*2);
  bf16* w2b  = (bf16*)alloc((size_t)4*H_*H_*2);
  char* qreg = alloc((size_t)A_*H_*2*4);               // q | k | vt | ao  (aliased by h)
  bf16* q  = (bf16*)qreg;
  bf16* kb = q  + (size_t)A_*H_;
  bf16* vt = kb + (size_t)A_*H_;
  bf16* ao = vt + (size_t)A_*H_;
  bf16* hbuf = q;                                      // [8192,3072] alias, live after ao consumed
  float* y1  = (float*)alloc((size_t)A_*H_*4);         // out_proj+res; reused for ffn2 out
  float* x1f = (float*)alloc((size_t)A_*H_*4);
  bf16*  x1b = (bf16*)alloc((size_t)A_*H_*2);

  // conversions (all sizes divisible by 1024)
  k_f32_bf16<<<A_*H_/1024,      256, 0, stream>>>(x,     xb,   A_*H_);
  k_f32_bf16<<<3*H_*H_/1024,    256, 0, stream>>>(w_qkv, wqkv, 3*H_*H_);
  k_f32_bf16<<<H_*H_/1024,      256, 0, stream>>>(w_out, wo,   H_*H_);
  k_f32_bf16<<<4*H_*H_/1024,    256, 0, stream>>>(w1,    w1b,  4*H_*H_);
  k_f32_bf16<<<4*H_*H_/1024,    256, 0, stream>>>(w2,    w2b,  4*H_*H_);

  // QKV projection + scatter
  k_gemm<0><<<dim3(3*H_/128, A_/128), 256, 0, stream>>>(xb, wqkv, b_qkv, nullptr,
      nullptr, nullptr, q, kb, vt, A_, 3*H_, H_);
  // scores + softmax -> P (d_out)
  k_attn_scores<<<dim3(B_*NH_, S_/64), 256, 0, stream>>>(q, kb, mask, P);
  // PV -> attn_out
  k_attn_pv<<<dim3(B_*NH_, S_/64), 256, 0, stream>>>(P, vt, ao);
  // out_proj + residual(x)
  k_gemm<1><<<dim3(H_/128, A_/128), 256, 0, stream>>>(ao, wo, b_out, x,
      y1, nullptr, nullptr, nullptr, nullptr, A_, H_, H_);
  k_layernorm<<<A_, 256, 0, stream>>>(y1, ln1g, ln1b, x1f, x1b);
  // FFN
  k_gemm<2><<<dim3(4*H_/128, A_/128), 256, 0, stream>>>(x1b, w1b, b1, nullptr,
      nullptr, hbuf, nullptr, nullptr, nullptr, A_, 4*H_, H_);
  k_gemm<1><<<dim3(H_/128, A_/128), 256, 0, stream>>>(hbuf, w2b, b2, x1f,
      y1, nullptr, nullptr, nullptr, nullptr, A_, H_, 4*H_);
  k_layernorm<<<A_, 256, 0, stream>>>(y1, ln2g, ln2b, xout, nullptr);
}

// Round 2
// 405.617 us; speedup vs baseline: 1.1202x; 1.1202x over previous
//
#include <hip/hip_runtime.h>
#include <hip/hip_bf16.h>
#include <math.h>

typedef __bf16 bf16;
typedef __attribute__((ext_vector_type(8))) __bf16 bf16x8;
typedef __attribute__((ext_vector_type(4))) __bf16 bf16x4;
typedef __attribute__((ext_vector_type(4))) float f32x4;

#define B_  16
#define S_  512
#define H_  768
#define NH_ 12
#define HD_ 64
#define A_  (B_*S_)   // 8192 token rows

// async global->LDS, 16B per lane; LDS dest = wave-uniform base + lane*16
__device__ __forceinline__ void gload_lds16(const void* g, void* l) {
  __builtin_amdgcn_global_load_lds((const __attribute__((address_space(1))) void*)g,
                                   (__attribute__((address_space(3))) void*)l, 16, 0, 0);
}

// ---------------- generic 128x128 bf16 MFMA GEMM: C = A @ Bt^T (+bias, epilogues) ----
// EPI 0: QKV scatter -> q[B,NH,S,HD], k[B,NH,S,HD], vt[B,NH,HD,S] (all bf16)
// EPI 1: outF = acc + bias + res   (fp32)
// EPI 2: outB = gelu(acc + bias)   (bf16)
template<int EPI>
__global__ __launch_bounds__(256) void k_gemm(
    const bf16* __restrict__ Amat, const bf16* __restrict__ Bt,
    const float* __restrict__ bias, const float* __restrict__ res,
    float* __restrict__ outF, bf16* __restrict__ outB,
    bf16* __restrict__ outQ, bf16* __restrict__ outK, bf16* __restrict__ outVT,
    int M, int N, int K)
{
  __shared__ __align__(16) bf16 As[128*32];
  __shared__ __align__(16) bf16 Bs[128*32];
  const int tid = threadIdx.x;
  const int w = tid >> 6, l = tid & 63;
  const int lr = l & 15, lg = l >> 4;
  const int row0 = blockIdx.y * 128, col0 = blockIdx.x * 128;
  const int wm = w >> 1, wn = w & 1;

  f32x4 acc[4][4] = {};

  for (int kk = 0; kk < K; kk += 32) {
#pragma unroll
    for (int j = 0; j < 2; ++j) {
      const int c = (w*2 + j)*64 + l;       // chunk id 0..511 (16B each)
      const int r = c >> 2;                 // tile row 0..127
      const int cc = (c & 3) * 8;           // col element offset
      gload_lds16(Amat + (size_t)(row0 + r)*K + kk + cc, As + (w*2 + j)*512);
      gload_lds16(Bt   + (size_t)(col0 + r)*K + kk + cc, Bs + (w*2 + j)*512);
    }
    __syncthreads();
    bf16x8 af[4], bfr[4];
    const bf16* Ab = As + (wm*64 + lr)*32 + lg*8;
    const bf16* Bb = Bs + (wn*64 + lr)*32 + lg*8;
#pragma unroll
    for (int t = 0; t < 4; ++t) {
      af[t]  = *(const bf16x8*)(Ab + t*512);   // +16 rows
      bfr[t] = *(const bf16x8*)(Bb + t*512);
    }
#pragma unroll
    for (int mt = 0; mt < 4; ++mt)
#pragma unroll
      for (int nt = 0; nt < 4; ++nt)
        acc[mt][nt] = __builtin_amdgcn_mfma_f32_16x16x32_bf16(af[mt], bfr[nt], acc[mt][nt], 0, 0, 0);
    __syncthreads();
  }

#pragma unroll
  for (int mt = 0; mt < 4; ++mt) {
#pragma unroll
    for (int nt = 0; nt < 4; ++nt) {
#pragma unroll
      for (int i = 0; i < 4; ++i) {
        const int row = row0 + wm*64 + mt*16 + lg*4 + i;
        const int col = col0 + wn*64 + nt*16 + lr;
        float v = acc[mt][nt][i] + bias[col];
        if constexpr (EPI == 1) {
          v += res[(size_t)row*N + col];
          outF[(size_t)row*N + col] = v;
        } else if constexpr (EPI == 2) {
          v = 0.5f * v * (1.0f + erff(v * 0.7071067811865475f));
          outB[(size_t)row*N + col] = (bf16)v;
        } else {
          const int b = row >> 9, s = row & 511;
          const int which = col / H_;
          const int hcol = col - which * H_;
          const int h = hcol >> 6, d = hcol & 63;
          const size_t bh = (size_t)b * NH_ + h;
          if (which == 0)      outQ[(bh*S_ + s)*HD_ + d] = (bf16)v;
          else if (which == 1) outK[(bh*S_ + s)*HD_ + d] = (bf16)v;
          else                 outVT[(bh*HD_ + d)*S_ + s] = (bf16)v;
        }
      }
    }
  }
}

// ---------------- fused attention: scores -> softmax -> P (d_out) -> PV -> AO -------
// One block per (bh, qt): 64 q-rows, full 512 k. 4 waves, wave w owns q-rows w*16..+15.
// Swapped QK^T: acc[ct] = mfma(K[ct*16..+15], Q)  ->  lane holds P[q=l&15][k=ct*16+hi*4+i]
// PV uses a permuted k-slot order so acc registers feed the A-fragment directly.
__global__ __launch_bounds__(256) void k_attn_fused(
    const bf16* __restrict__ Qm, const bf16* __restrict__ Km, const bf16* __restrict__ VT,
    const unsigned char* __restrict__ mask, float* __restrict__ P, bf16* __restrict__ AO)
{
  __shared__ __align__(16) bf16 KVs[512*64];  // K rows, later reused for V^T (64x512)
  __shared__ __align__(16) bf16 Qs[64*64];
  const int tid = threadIdx.x, w = tid >> 6, l = tid & 63;
  const int lr = l & 15, hi = l >> 4;
  const int bh = blockIdx.x, qt = blockIdx.y;
  const int b = bh / NH_, h = bh - b * NH_;
  const int swz = (lr & 7) << 4;              // read-side byte XOR (row&7)<<4, row%8==lr%8 everywhere

  // --- stage K [512][64] and Q [64][64], source pre-swizzled so linear LDS dest + XOR reads work
  const bf16* Kg = Km + (size_t)bh * S_ * HD_;
  const bf16* Qg = Qm + (size_t)bh * S_ * HD_ + (size_t)qt * 64 * HD_;
#pragma unroll
  for (int rnd = 0; rnd < 16; ++rnd) {
    const int c = rnd*256 + tid;              // 16B chunk id, row = c>>3 (128B rows)
    const int row = c >> 3, col16 = (c & 7) ^ (row & 7);
    gload_lds16(Kg + row*HD_ + col16*8, KVs + (rnd*4 + w)*512);
  }
#pragma unroll
  for (int rnd = 0; rnd < 2; ++rnd) {
    const int c = rnd*256 + tid;
    const int row = c >> 3, col16 = (c & 7) ^ (row & 7);
    gload_lds16(Qg + row*HD_ + col16*8, Qs + (rnd*4 + w)*512);
  }
  __syncthreads();

  // --- QK^T (swapped operands) ---
  const char* qrow = (const char*)(Qs + (w*16 + lr)*64);
  bf16x8 qf0 = *(const bf16x8*)(qrow + ((hi*16) ^ swz));
  bf16x8 qf1 = *(const bf16x8*)(qrow + ((64 + hi*16) ^ swz));
  f32x4 acc[32];
#pragma unroll
  for (int ct = 0; ct < 32; ++ct) acc[ct] = f32x4{0.f,0.f,0.f,0.f};
#pragma unroll
  for (int ct = 0; ct < 32; ++ct) {
    const char* kb = (const char*)(KVs + (ct*16 + lr)*64);
    bf16x8 a0 = *(const bf16x8*)(kb + ((hi*16) ^ swz));
    bf16x8 a1 = *(const bf16x8*)(kb + ((64 + hi*16) ^ swz));
    acc[ct] = __builtin_amdgcn_mfma_f32_16x16x32_bf16(a0, qf0, acc[ct], 0, 0, 0);
    acc[ct] = __builtin_amdgcn_mfma_f32_16x16x32_bf16(a1, qf1, acc[ct], 0, 0, 0);
  }
  __syncthreads();   // all waves done reading KVs

  // --- issue V^T [64][512] staging into KVs (completes under softmax; drained by next barrier)
  const bf16* Vg = VT + (size_t)bh * HD_ * S_;
#pragma unroll
  for (int rnd = 0; rnd < 16; ++rnd) {
    const int c = rnd*256 + tid;              // row = c>>6 (1024B rows)
    const int row = c >> 6, col16 = (c & 63) ^ (row & 7);
    gload_lds16(Vg + row*S_ + col16*8, KVs + (rnd*4 + w)*512);
  }

  // --- mask + scale + softmax (row = q = l&15; partners at lanes ^16, ^32) ---
  const unsigned char* mrow = mask + b * S_;
  float mx = -1e30f;
#pragma unroll
  for (int ct = 0; ct < 32; ++ct) {
    const unsigned mk4 = *(const unsigned*)(mrow + ct*16 + hi*4);
#pragma unroll
    for (int i = 0; i < 4; ++i) {
      float v = acc[ct][i] * 0.125f;
      if ((mk4 >> (8*i)) & 0xff) v = -1e30f;
      acc[ct][i] = v;
      mx = fmaxf(mx, v);
    }
  }
  mx = fmaxf(mx, __shfl_xor(mx, 16));
  mx = fmaxf(mx, __shfl_xor(mx, 32));
  float sum = 0.f;
#pragma unroll
  for (int ct = 0; ct < 32; ++ct)
#pragma unroll
    for (int i = 0; i < 4; ++i) { float e = __expf(acc[ct][i] - mx); acc[ct][i] = e; sum += e; }
  sum += __shfl_xor(sum, 16);
  sum += __shfl_xor(sum, 32);
  const float inv = 1.f / sum;

  float* prow = P + ((size_t)bh*S_ + (size_t)qt*64 + w*16 + lr) * S_;
#pragma unroll
  for (int ct = 0; ct < 32; ++ct) {
#pragma unroll
    for (int i = 0; i < 4; ++i) acc[ct][i] *= inv;
    *(f32x4*)(prow + ct*16 + hi*4) = acc[ct];
  }
  __syncthreads();   // V staged (barrier drains vmcnt)

  // --- PV: O[q][d] = sum_k P[q][k] V[k][d]; k-slot permutation matches acc layout ---
  f32x4 o[4] = {};
#pragma unroll
  for (int c = 0; c < 16; ++c) {
    bf16x8 pa;
#pragma unroll
    for (int i = 0; i < 4; ++i) { pa[i] = (bf16)acc[2*c][i]; pa[4+i] = (bf16)acc[2*c+1][i]; }
    const int cb0 = (64*c + 8*hi) ^ swz;         // k = 32c + hi*4 + j   (j=0..3)
    const int cb1 = (64*c + 32 + 8*hi) ^ swz;    // k = 32c + 16 + hi*4 + j
#pragma unroll
    for (int nt = 0; nt < 4; ++nt) {
      const char* vb = (const char*)(KVs + (nt*16 + lr)*512);
      bf16x4 v0 = *(const bf16x4*)(vb + cb0);
      bf16x4 v1 = *(const bf16x4*)(vb + cb1);
      bf16x8 vf = {v0[0],v0[1],v0[2],v0[3], v1[0],v1[1],v1[2],v1[3]};
      o[nt] = __builtin_amdgcn_mfma_f32_16x16x32_bf16(pa, vf, o[nt], 0, 0, 0);
    }
  }

  bf16* aorow = AO + ((size_t)(b*S_ + qt*64 + w*16))*H_ + h*HD_;
#pragma unroll
  for (int nt = 0; nt < 4; ++nt)
#pragma unroll
    for (int i = 0; i < 4; ++i)
      aorow[(size_t)(hi*4 + i)*H_ + nt*16 + lr] = (bf16)o[nt][i];
}

// ---------------- LayerNorm over H=768, one row per block ---------------------------
__global__ __launch_bounds__(256) void k_layernorm(
    const float* __restrict__ X, const float* __restrict__ g, const float* __restrict__ bta,
    float* __restrict__ outF, bf16* __restrict__ outB)
{
  const int row = blockIdx.x;
  const int tid = threadIdx.x;
  const float* x = X + (size_t)row * H_;
  float v[3]; float s = 0.f, ss = 0.f;
#pragma unroll
  for (int j = 0; j < 3; ++j) { v[j] = x[tid + j*256]; s += v[j]; ss += v[j]*v[j]; }
#pragma unroll
  for (int d = 1; d < 64; d <<= 1) { s += __shfl_xor(s, d); ss += __shfl_xor(ss, d); }
  __shared__ float red[8];
  const int w = tid >> 6, l = tid & 63;
  if (l == 0) { red[w] = s; red[4 + w] = ss; }
  __syncthreads();
  s  = red[0] + red[1] + red[2] + red[3];
  ss = red[4] + red[5] + red[6] + red[7];
  const float mean = s * (1.f / H_);
  const float var  = ss * (1.f / H_) - mean * mean;
  const float inv  = rsqrtf(var + 1e-5f);
#pragma unroll
  for (int j = 0; j < 3; ++j) {
    const int c = tid + j*256;
    const float y = (v[j] - mean) * inv * g[c] + bta[c];
    if (outF) outF[(size_t)row*H_ + c] = y;
    if (outB) outB[(size_t)row*H_ + c] = (bf16)y;
  }
}

// ---------------- fp32 -> bf16 convert ----------------------------------------------
__global__ void k_f32_bf16(const float* __restrict__ in, bf16* __restrict__ out, int n) {
  const int i = (blockIdx.x * 256 + threadIdx.x) * 4;
  if (i < n) {
    const float4 vv = *(const float4*)(in + i);
    bf16x4 o; o[0]=(bf16)vv.x; o[1]=(bf16)vv.y; o[2]=(bf16)vv.z; o[3]=(bf16)vv.w;
    *(bf16x4*)(out + i) = o;
  }
}

extern "C" void kernel_launch(void* const* d_in, const int* in_sizes, int n_in,
                              void* d_out, int out_size, void* d_ws, size_t ws_size,
                              hipStream_t stream) {
  const float* x      = (const float*)d_in[0];
  const unsigned char* mask = (const unsigned char*)d_in[1];
  const float* w_qkv  = (const float*)d_in[2];
  const float* b_qkv  = (const float*)d_in[3];
  const float* w_out  = (const float*)d_in[4];
  const float* b_out  = (const float*)d_in[5];
  const float* w1     = (const float*)d_in[6];
  const float* b1     = (const float*)d_in[7];
  const float* w2     = (const float*)d_in[8];
  const float* b2     = (const float*)d_in[9];
  const float* ln1g   = (const float*)d_in[10];
  const float* ln1b   = (const float*)d_in[11];
  const float* ln2g   = (const float*)d_in[12];
  const float* ln2b   = (const float*)d_in[13];

  float* xout = (float*)d_out;                      // [8192, 768]
  float* P    = xout + (size_t)A_ * H_;             // [192, 512, 512] attn weights

  char* ws = (char*)d_ws;
  size_t off = 0;
  auto alloc = [&](size_t bytes) { char* p = ws + off; off += (bytes + 255) & ~255ull; return p; };

  bf16* xb   = (bf16*)alloc((size_t)A_*H_*2);          // x as bf16
  bf16* wqkv = (bf16*)alloc((size_t)3*H_*H_*2);
  bf16* wo   = (bf16*)alloc((size_t)H_*H_*2);
  bf16* w1b  = (bf16*)alloc((size_t)4*H_*H_*2);
  bf16* w2b  = (bf16*)alloc((size_t)4*H_*H_*2);
  char* qreg = alloc((size_t)A_*H_*2*4);               // q | k | vt | ao
  bf16* q  = (bf16*)qreg;
  bf16* kb = q  + (size_t)A_*H_;
  bf16* vt = kb + (size_t)A_*H_;
  bf16* ao = vt + (size_t)A_*H_;
  bf16* hbuf = q;                                      // [8192,3072] alias, live after ao consumed
  float* y1  = (float*)alloc((size_t)A_*H_*4);
  float* x1f = (float*)alloc((size_t)A_*H_*4);
  bf16*  x1b = (bf16*)alloc((size_t)A_*H_*2);

  // conversions
  k_f32_bf16<<<A_*H_/1024,      256, 0, stream>>>(x,     xb,   A_*H_);
  k_f32_bf16<<<3*H_*H_/1024,    256, 0, stream>>>(w_qkv, wqkv, 3*H_*H_);
  k_f32_bf16<<<H_*H_/1024,      256, 0, stream>>>(w_out, wo,   H_*H_);
  k_f32_bf16<<<4*H_*H_/1024,    256, 0, stream>>>(w1,    w1b,  4*H_*H_);
  k_f32_bf16<<<4*H_*H_/1024,    256, 0, stream>>>(w2,    w2b,  4*H_*H_);

  // QKV projection + scatter
  k_gemm<0><<<dim3(3*H_/128, A_/128), 256, 0, stream>>>(xb, wqkv, b_qkv, nullptr,
      nullptr, nullptr, q, kb, vt, A_, 3*H_, H_);
  // fused scores + softmax (P -> d_out) + PV -> attn_out
  k_attn_fused<<<dim3(B_*NH_, S_/64), 256, 0, stream>>>(q, kb, vt, mask, P, ao);
  // out_proj + residual(x)
  k_gemm<1><<<dim3(H_/128, A_/128), 256, 0, stream>>>(ao, wo, b_out, x,
      y1, nullptr, nullptr, nullptr, nullptr, A_, H_, H_);
  k_layernorm<<<A_, 256, 0, stream>>>(y1, ln1g, ln1b, x1f, x1b);
  // FFN
  k_gemm<2><<<dim3(4*H_/128, A_/128), 256, 0, stream>>>(x1b, w1b, b1, nullptr,
      nullptr, hbuf, nullptr, nullptr, nullptr, A_, 4*H_, H_);
  k_gemm<1><<<dim3(H_/128, A_/128), 256, 0, stream>>>(hbuf, w2b, b2, x1f,
      y1, nullptr, nullptr, nullptr, nullptr, A_, H_, 4*H_);
  k_layernorm<<<A_, 256, 0, stream>>>(y1, ln2g, ln2b, xout, nullptr);
}

// Round 3
// 354.667 us; speedup vs baseline: 1.2811x; 1.1437x over previous
//
#include <hip/hip_runtime.h>
#include <hip/hip_bf16.h>
#include <math.h>

typedef __bf16 bf16;
typedef __attribute__((ext_vector_type(8))) __bf16 bf16x8;
typedef __attribute__((ext_vector_type(4))) __bf16 bf16x4;
typedef __attribute__((ext_vector_type(4))) float f32x4;

#define B_  16
#define S_  512
#define H_  768
#define NH_ 12
#define HD_ 64
#define A_  (B_*S_)   // 8192 token rows

// async global->LDS, 16B per lane; LDS dest = wave-uniform base + lane*16
__device__ __forceinline__ void gload_lds16(const void* g, void* l) {
  __builtin_amdgcn_global_load_lds((const __attribute__((address_space(1))) void*)g,
                                   (__attribute__((address_space(3))) void*)l, 16, 0, 0);
}

// =====================================================================================
// Phase-pipelined GEMM: C[M,N] = A[M,K] @ Bt[N,K]^T (+bias, epilogues)
// BM=128, BN=192, BK=64. 512 threads = 8 waves (2M x 4N). Per-wave out 64x48 (4x3 frags).
// LDS: 3 slots x (A[128][64] + B[192][64]) bf16 = 120 KB, triple-buffered K-tiles.
// Staging of tile t+2 issued during tile t into slot (t+2)%3 (vacated by tile t-1 at its
// trailing barrier -> issue-after-barrier => DMA cannot land before readers finished).
// Boundary: s_waitcnt vmcnt(5) (t+2's 5 units in flight) + s_barrier => tile t+1 landed.
// XOR swizzle: LDS col-slot = global-slot ^ (row&7), both sides; 2-way conflicts (free).
// EPI 0: QKV scatter -> q[B,NH,S,HD], k[B,NH,S,HD], vt[B,NH,HD,S] (bf16)
// EPI 1: outF = acc + bias + res   (fp32)
// EPI 2: outB = gelu(acc + bias)   (bf16)
// =====================================================================================
#define GBM 128
#define GBN 192
#define GBK 64
#define SLOT_E 20480   // elems per LDS slot: A 8192 + B 12288

template<int EPI>
__global__ __launch_bounds__(512, 2) void k_gemm(
    const bf16* __restrict__ Amat, const bf16* __restrict__ Bt,
    const float* __restrict__ bias, const float* __restrict__ res,
    float* __restrict__ outF, bf16* __restrict__ outB,
    bf16* __restrict__ outQ, bf16* __restrict__ outK, bf16* __restrict__ outVT,
    int M, int N, int K)
{
  __shared__ __align__(16) bf16 LDS[3*SLOT_E];
  const int tid = threadIdx.x;
  const int w = tid >> 6, l = tid & 63;
  const int lr = l & 15, hi = l >> 4;
  const int wm = w >> 2, wn = w & 3;

  // XCD-aware bijective swizzle (gridDim.x % 8 == 0 for all our launches)
  const int nbx = N / GBN;
  const int cpx = gridDim.x >> 3;
  const int sw  = (blockIdx.x & 7) * cpx + (blockIdx.x >> 3);
  const int by = sw / nbx, bx = sw - by * nbx;
  const int row0 = by * GBM, col0 = bx * GBN;
  const int NT = K / GBK;

  // stage unit u (0..4) of K-tile t: u 0-1 = A halves, u 2-4 = B thirds
  auto stage = [&](int t, int u) {
    bf16* slot = LDS + (t % 3) * SLOT_E;
    if (u < 2) {
      const int fc = u*512 + tid;                 // 0..1023
      const int r = fc >> 3, s = fc & 7;
      const int gs = s ^ (r & 7);
      gload_lds16(Amat + (size_t)(row0 + r)*K + t*GBK + gs*8,
                  slot + (size_t)fc*8 - (size_t)l*8);   // wave-uniform base + lane*16
    } else {
      const int fc = (u-2)*512 + tid;             // 0..1535
      const int r = fc >> 3, s = fc & 7;
      const int gs = s ^ (r & 7);
      gload_lds16(Bt + (size_t)(col0 + r)*K + t*GBK + gs*8,
                  slot + 8192 + (size_t)fc*8 - (size_t)l*8);
    }
  };

  f32x4 acc[4][3] = {};

  // prologue: stage tiles 0 and 1 (5 units each), wait for tile 0
#pragma unroll
  for (int u = 0; u < 5; ++u) stage(0, u);
#pragma unroll
  for (int u = 0; u < 5; ++u) stage(1, u);
  asm volatile("s_waitcnt vmcnt(5)" ::: "memory");
  __builtin_amdgcn_s_barrier();

  for (int t = 0; t < NT; ++t) {
    const bf16* slot = LDS + (t % 3) * SLOT_E;
    const bool pre = (t + 2 < NT);

    // ---- phase 0 (k-step 0) ----
    bf16x8 af[4], bfr[3];
#pragma unroll
    for (int m = 0; m < 4; ++m) {
      const int r = wm*64 + m*16 + lr;
      af[m] = *(const bf16x8*)(slot + r*64 + (hi ^ (r & 7))*8);
    }
#pragma unroll
    for (int n = 0; n < 3; ++n) {
      const int r = wn*48 + n*16 + lr;
      bfr[n] = *(const bf16x8*)(slot + 8192 + r*64 + (hi ^ (r & 7))*8);
    }
    if (pre) { stage(t+2, 0); stage(t+2, 1); stage(t+2, 2); }
    __builtin_amdgcn_s_barrier();
    asm volatile("s_waitcnt lgkmcnt(0)" ::: "memory");
    __builtin_amdgcn_sched_barrier(0);
    __builtin_amdgcn_s_setprio(1);
#pragma unroll
    for (int m = 0; m < 4; ++m)
#pragma unroll
      for (int n = 0; n < 3; ++n)
        acc[m][n] = __builtin_amdgcn_mfma_f32_16x16x32_bf16(af[m], bfr[n], acc[m][n], 0, 0, 0);
    __builtin_amdgcn_s_setprio(0);
    __builtin_amdgcn_s_barrier();

    // ---- phase 1 (k-step 1) ----
#pragma unroll
    for (int m = 0; m < 4; ++m) {
      const int r = wm*64 + m*16 + lr;
      af[m] = *(const bf16x8*)(slot + r*64 + ((4 + hi) ^ (r & 7))*8);
    }
#pragma unroll
    for (int n = 0; n < 3; ++n) {
      const int r = wn*48 + n*16 + lr;
      bfr[n] = *(const bf16x8*)(slot + 8192 + r*64 + ((4 + hi) ^ (r & 7))*8);
    }
    if (pre) { stage(t+2, 3); stage(t+2, 4); }
    __builtin_amdgcn_s_barrier();
    asm volatile("s_waitcnt lgkmcnt(0)" ::: "memory");
    __builtin_amdgcn_sched_barrier(0);
    __builtin_amdgcn_s_setprio(1);
#pragma unroll
    for (int m = 0; m < 4; ++m)
#pragma unroll
      for (int n = 0; n < 3; ++n)
        acc[m][n] = __builtin_amdgcn_mfma_f32_16x16x32_bf16(af[m], bfr[n], acc[m][n], 0, 0, 0);
    __builtin_amdgcn_s_setprio(0);

    // ---- K-tile boundary: tile t+1 must have landed ----
    if (t < NT - 1) {
      if (pre) asm volatile("s_waitcnt vmcnt(5)" ::: "memory");
      else     asm volatile("s_waitcnt vmcnt(0)" ::: "memory");
      __builtin_amdgcn_s_barrier();
    }
  }

  // ---- epilogue ----
#pragma unroll
  for (int m = 0; m < 4; ++m) {
#pragma unroll
    for (int n = 0; n < 3; ++n) {
#pragma unroll
      for (int i = 0; i < 4; ++i) {
        const int row = row0 + wm*64 + m*16 + hi*4 + i;
        const int col = col0 + wn*48 + n*16 + lr;
        float v = acc[m][n][i] + bias[col];
        if constexpr (EPI == 1) {
          v += res[(size_t)row*N + col];
          outF[(size_t)row*N + col] = v;
        } else if constexpr (EPI == 2) {
          v = 0.5f * v * (1.0f + erff(v * 0.7071067811865475f));
          outB[(size_t)row*N + col] = (bf16)v;
        } else {
          const int b = row >> 9, s = row & 511;
          const int which = col / H_;
          const int hcol = col - which * H_;
          const int h = hcol >> 6, d = hcol & 63;
          const size_t bh = (size_t)b * NH_ + h;
          if (which == 0)      outQ[(bh*S_ + s)*HD_ + d] = (bf16)v;
          else if (which == 1) outK[(bh*S_ + s)*HD_ + d] = (bf16)v;
          else                 outVT[(bh*HD_ + d)*S_ + s] = (bf16)v;
        }
      }
    }
  }
}

// ---------------- fused attention: scores -> softmax -> P (d_out) -> PV -> AO -------
__global__ __launch_bounds__(256) void k_attn_fused(
    const bf16* __restrict__ Qm, const bf16* __restrict__ Km, const bf16* __restrict__ VT,
    const unsigned char* __restrict__ mask, float* __restrict__ P, bf16* __restrict__ AO)
{
  __shared__ __align__(16) bf16 KVs[512*64];  // K rows, later reused for V^T (64x512)
  __shared__ __align__(16) bf16 Qs[64*64];
  const int tid = threadIdx.x, w = tid >> 6, l = tid & 63;
  const int lr = l & 15, hi = l >> 4;
  const int bh = blockIdx.x, qt = blockIdx.y;
  const int b = bh / NH_, h = bh - b * NH_;
  const int swz = (lr & 7) << 4;

  const bf16* Kg = Km + (size_t)bh * S_ * HD_;
  const bf16* Qg = Qm + (size_t)bh * S_ * HD_ + (size_t)qt * 64 * HD_;
#pragma unroll
  for (int rnd = 0; rnd < 16; ++rnd) {
    const int c = rnd*256 + tid;
    const int row = c >> 3, col16 = (c & 7) ^ (row & 7);
    gload_lds16(Kg + row*HD_ + col16*8, KVs + (rnd*4 + w)*512);
  }
#pragma unroll
  for (int rnd = 0; rnd < 2; ++rnd) {
    const int c = rnd*256 + tid;
    const int row = c >> 3, col16 = (c & 7) ^ (row & 7);
    gload_lds16(Qg + row*HD_ + col16*8, Qs + (rnd*4 + w)*512);
  }
  __syncthreads();

  const char* qrow = (const char*)(Qs + (w*16 + lr)*64);
  bf16x8 qf0 = *(const bf16x8*)(qrow + ((hi*16) ^ swz));
  bf16x8 qf1 = *(const bf16x8*)(qrow + ((64 + hi*16) ^ swz));
  f32x4 acc[32];
#pragma unroll
  for (int ct = 0; ct < 32; ++ct) acc[ct] = f32x4{0.f,0.f,0.f,0.f};
#pragma unroll
  for (int ct = 0; ct < 32; ++ct) {
    const char* kb = (const char*)(KVs + (ct*16 + lr)*64);
    bf16x8 a0 = *(const bf16x8*)(kb + ((hi*16) ^ swz));
    bf16x8 a1 = *(const bf16x8*)(kb + ((64 + hi*16) ^ swz));
    acc[ct] = __builtin_amdgcn_mfma_f32_16x16x32_bf16(a0, qf0, acc[ct], 0, 0, 0);
    acc[ct] = __builtin_amdgcn_mfma_f32_16x16x32_bf16(a1, qf1, acc[ct], 0, 0, 0);
  }
  __syncthreads();

  const bf16* Vg = VT + (size_t)bh * HD_ * S_;
#pragma unroll
  for (int rnd = 0; rnd < 16; ++rnd) {
    const int c = rnd*256 + tid;
    const int row = c >> 6, col16 = (c & 63) ^ (row & 7);
    gload_lds16(Vg + row*S_ + col16*8, KVs + (rnd*4 + w)*512);
  }

  const unsigned char* mrow = mask + b * S_;
  float mx = -1e30f;
#pragma unroll
  for (int ct = 0; ct < 32; ++ct) {
    const unsigned mk4 = *(const unsigned*)(mrow + ct*16 + hi*4);
#pragma unroll
    for (int i = 0; i < 4; ++i) {
      float v = acc[ct][i] * 0.125f;
      if ((mk4 >> (8*i)) & 0xff) v = -1e30f;
      acc[ct][i] = v;
      mx = fmaxf(mx, v);
    }
  }
  mx = fmaxf(mx, __shfl_xor(mx, 16));
  mx = fmaxf(mx, __shfl_xor(mx, 32));
  float sum = 0.f;
#pragma unroll
  for (int ct = 0; ct < 32; ++ct)
#pragma unroll
    for (int i = 0; i < 4; ++i) { float e = __expf(acc[ct][i] - mx); acc[ct][i] = e; sum += e; }
  sum += __shfl_xor(sum, 16);
  sum += __shfl_xor(sum, 32);
  const float inv = 1.f / sum;

  float* prow = P + ((size_t)bh*S_ + (size_t)qt*64 + w*16 + lr) * S_;
#pragma unroll
  for (int ct = 0; ct < 32; ++ct) {
#pragma unroll
    for (int i = 0; i < 4; ++i) acc[ct][i] *= inv;
    *(f32x4*)(prow + ct*16 + hi*4) = acc[ct];
  }
  __syncthreads();

  f32x4 o[4] = {};
#pragma unroll
  for (int c = 0; c < 16; ++c) {
    bf16x8 pa;
#pragma unroll
    for (int i = 0; i < 4; ++i) { pa[i] = (bf16)acc[2*c][i]; pa[4+i] = (bf16)acc[2*c+1][i]; }
    const int cb0 = (64*c + 8*hi) ^ swz;
    const int cb1 = (64*c + 32 + 8*hi) ^ swz;
#pragma unroll
    for (int nt = 0; nt < 4; ++nt) {
      const char* vb = (const char*)(KVs + (nt*16 + lr)*512);
      bf16x4 v0 = *(const bf16x4*)(vb + cb0);
      bf16x4 v1 = *(const bf16x4*)(vb + cb1);
      bf16x8 vf = {v0[0],v0[1],v0[2],v0[3], v1[0],v1[1],v1[2],v1[3]};
      o[nt] = __builtin_amdgcn_mfma_f32_16x16x32_bf16(pa, vf, o[nt], 0, 0, 0);
    }
  }

  bf16* aorow = AO + ((size_t)(b*S_ + qt*64 + w*16))*H_ + h*HD_;
#pragma unroll
  for (int nt = 0; nt < 4; ++nt)
#pragma unroll
    for (int i = 0; i < 4; ++i)
      aorow[(size_t)(hi*4 + i)*H_ + nt*16 + lr] = (bf16)o[nt][i];
}

// ---------------- LayerNorm over H=768, one row per block ---------------------------
__global__ __launch_bounds__(256) void k_layernorm(
    const float* __restrict__ X, const float* __restrict__ g, const float* __restrict__ bta,
    float* __restrict__ outF, bf16* __restrict__ outB)
{
  const int row = blockIdx.x;
  const int tid = threadIdx.x;
  const float* x = X + (size_t)row * H_;
  float v[3]; float s = 0.f, ss = 0.f;
#pragma unroll
  for (int j = 0; j < 3; ++j) { v[j] = x[tid + j*256]; s += v[j]; ss += v[j]*v[j]; }
#pragma unroll
  for (int d = 1; d < 64; d <<= 1) { s += __shfl_xor(s, d); ss += __shfl_xor(ss, d); }
  __shared__ float red[8];
  const int w = tid >> 6, l = tid & 63;
  if (l == 0) { red[w] = s; red[4 + w] = ss; }
  __syncthreads();
  s  = red[0] + red[1] + red[2] + red[3];
  ss = red[4] + red[5] + red[6] + red[7];
  const float mean = s * (1.f / H_);
  const float var  = ss * (1.f / H_) - mean * mean;
  const float inv  = rsqrtf(var + 1e-5f);
#pragma unroll
  for (int j = 0; j < 3; ++j) {
    const int c = tid + j*256;
    const float y = (v[j] - mean) * inv * g[c] + bta[c];
    if (outF) outF[(size_t)row*H_ + c] = y;
    if (outB) outB[(size_t)row*H_ + c] = (bf16)y;
  }
}

// ---------------- fp32 -> bf16 convert ----------------------------------------------
__global__ void k_f32_bf16(const float* __restrict__ in, bf16* __restrict__ out, int n) {
  const int i = (blockIdx.x * 256 + threadIdx.x) * 4;
  if (i < n) {
    const float4 vv = *(const float4*)(in + i);
    bf16x4 o; o[0]=(bf16)vv.x; o[1]=(bf16)vv.y; o[2]=(bf16)vv.z; o[3]=(bf16)vv.w;
    *(bf16x4*)(out + i) = o;
  }
}

extern "C" void kernel_launch(void* const* d_in, const int* in_sizes, int n_in,
                              void* d_out, int out_size, void* d_ws, size_t ws_size,
                              hipStream_t stream) {
  const float* x      = (const float*)d_in[0];
  const unsigned char* mask = (const unsigned char*)d_in[1];
  const float* w_qkv  = (const float*)d_in[2];
  const float* b_qkv  = (const float*)d_in[3];
  const float* w_out  = (const float*)d_in[4];
  const float* b_out  = (const float*)d_in[5];
  const float* w1     = (const float*)d_in[6];
  const float* b1     = (const float*)d_in[7];
  const float* w2     = (const float*)d_in[8];
  const float* b2     = (const float*)d_in[9];
  const float* ln1g   = (const float*)d_in[10];
  const float* ln1b   = (const float*)d_in[11];
  const float* ln2g   = (const float*)d_in[12];
  const float* ln2b   = (const float*)d_in[13];

  float* xout = (float*)d_out;                      // [8192, 768]
  float* P    = xout + (size_t)A_ * H_;             // [192, 512, 512] attn weights

  char* ws = (char*)d_ws;
  size_t off = 0;
  auto alloc = [&](size_t bytes) { char* p = ws + off; off += (bytes + 255) & ~255ull; return p; };

  bf16* xb   = (bf16*)alloc((size_t)A_*H_*2);
  bf16* wqkv = (bf16*)alloc((size_t)3*H_*H_*2);
  bf16* wo   = (bf16*)alloc((size_t)H_*H_*2);
  bf16* w1b  = (bf16*)alloc((size_t)4*H_*H_*2);
  bf16* w2b  = (bf16*)alloc((size_t)4*H_*H_*2);
  char* qreg = alloc((size_t)A_*H_*2*4);               // q | k | vt | ao
  bf16* q  = (bf16*)qreg;
  bf16* kb = q  + (size_t)A_*H_;
  bf16* vt = kb + (size_t)A_*H_;
  bf16* ao = vt + (size_t)A_*H_;
  bf16* hbuf = q;                                      // [8192,3072] alias, live after ao consumed
  float* y1  = (float*)alloc((size_t)A_*H_*4);
  float* x1f = (float*)alloc((size_t)A_*H_*4);
  bf16*  x1b = (bf16*)alloc((size_t)A_*H_*2);

  // conversions
  k_f32_bf16<<<A_*H_/1024,      256, 0, stream>>>(x,     xb,   A_*H_);
  k_f32_bf16<<<3*H_*H_/1024,    256, 0, stream>>>(w_qkv, wqkv, 3*H_*H_);
  k_f32_bf16<<<H_*H_/1024,      256, 0, stream>>>(w_out, wo,   H_*H_);
  k_f32_bf16<<<4*H_*H_/1024,    256, 0, stream>>>(w1,    w1b,  4*H_*H_);
  k_f32_bf16<<<4*H_*H_/1024,    256, 0, stream>>>(w2,    w2b,  4*H_*H_);

  // QKV projection + scatter: M=8192, N=2304, K=768 -> grid 64*12=768 blocks
  k_gemm<0><<<(A_/GBM)*(3*H_/GBN), 512, 0, stream>>>(xb, wqkv, b_qkv, nullptr,
      nullptr, nullptr, q, kb, vt, A_, 3*H_, H_);
  // fused scores + softmax (P -> d_out) + PV -> attn_out
  k_attn_fused<<<dim3(B_*NH_, S_/64), 256, 0, stream>>>(q, kb, vt, mask, P, ao);
  // out_proj + residual(x): grid 64*4=256
  k_gemm<1><<<(A_/GBM)*(H_/GBN), 512, 0, stream>>>(ao, wo, b_out, x,
      y1, nullptr, nullptr, nullptr, nullptr, A_, H_, H_);
  k_layernorm<<<A_, 256, 0, stream>>>(y1, ln1g, ln1b, x1f, x1b);
  // FFN1: grid 64*16=1024
  k_gemm<2><<<(A_/GBM)*(4*H_/GBN), 512, 0, stream>>>(x1b, w1b, b1, nullptr,
      nullptr, hbuf, nullptr, nullptr, nullptr, A_, 4*H_, H_);
  // FFN2: grid 64*4=256, K=3072
  k_gemm<1><<<(A_/GBM)*(H_/GBN), 512, 0, stream>>>(hbuf, w2b, b2, x1f,
      y1, nullptr, nullptr, nullptr, nullptr, A_, H_, 4*H_);
  k_layernorm<<<A_, 256, 0, stream>>>(y1, ln2g, ln2b, xout, nullptr);
}

// Round 4
// 331.714 us; speedup vs baseline: 1.3697x; 1.0692x over previous
//
#include <hip/hip_runtime.h>
#include <hip/hip_bf16.h>
#include <math.h>

typedef __bf16 bf16;
typedef __attribute__((ext_vector_type(8))) __bf16 bf16x8;
typedef __attribute__((ext_vector_type(4))) __bf16 bf16x4;
typedef __attribute__((ext_vector_type(4))) float f32x4;

#define B_  16
#define S_  512
#define H_  768
#define NH_ 12
#define HD_ 64
#define A_  (B_*S_)   // 8192 token rows

// async global->LDS, 16B per lane; LDS dest = wave-uniform base + lane*16
__device__ __forceinline__ void gload_lds16(const void* g, void* l) {
  __builtin_amdgcn_global_load_lds((const __attribute__((address_space(1))) void*)g,
                                   (__attribute__((address_space(3))) void*)l, 16, 0, 0);
}

// =====================================================================================
// Phase-pipelined GEMM: C[M,N] = A[M,K] @ Bt[N,K]^T (+bias, epilogues)
// BM=128, BN_ in {192,256}, BK=64. 512 threads = 8 waves (2M x 4N).
// Per-wave out 64 x BN_/4 (4 x NFRAG fragments), NFRAG = BN_/64.
// LDS: 3 slots x (A[128][64] + B[BN_][64]) bf16, triple-buffered K-tiles.
// Stage of tile t+2 issued during tile t into the slot tile t-1 vacated at its trailing
// barrier (issue-after-barrier => DMA cannot land before readers finish).
// Boundary: s_waitcnt vmcnt(UNITS) (t+2 in flight) + s_barrier => tile t+1 landed.
// XOR swizzle: LDS col-slot = global-slot ^ (row&7), both sides; 2-way conflicts (free).
// EPI 0: QKV scatter -> q[B,NH,S,HD], k[B,NH,S,HD], vt[B,NH,HD,S] (bf16)
// EPI 1: outF = acc + bias + resF (fp32 residual)
// EPI 2: outB = gelu(acc + bias)  (bf16)
// EPI 3: outF = acc + bias + resB (bf16 residual)
// =====================================================================================
template<int EPI, int BN_>
__global__ __launch_bounds__(512, 2) void k_gemm(
    const bf16* __restrict__ Amat, const bf16* __restrict__ Bt,
    const float* __restrict__ bias, const float* __restrict__ resF,
    const bf16* __restrict__ resB,
    float* __restrict__ outF, bf16* __restrict__ outB,
    bf16* __restrict__ outQ, bf16* __restrict__ outK, bf16* __restrict__ outVT,
    int M, int N, int K)
{
  constexpr int NFRAG  = BN_ / 64;        // 3 or 4
  constexpr int UNITS  = 2 + NFRAG;       // 8KB stage units per K-tile
  constexpr int SLOT_E = 8192 + BN_ * 64; // elems per LDS slot
  constexpr int WN     = BN_ / 4;         // per-wave N extent
  __shared__ __align__(16) bf16 LDS[3 * SLOT_E];
  const int tid = threadIdx.x;
  const int w = tid >> 6, l = tid & 63;
  const int lr = l & 15, hi = l >> 4;
  const int wm = w >> 2, wn = w & 3;

  // XCD-aware bijective swizzle (gridDim.x % 8 == 0 for all our launches)
  const int nbx = N / BN_;
  const int cpx = gridDim.x >> 3;
  const int sw  = (blockIdx.x & 7) * cpx + (blockIdx.x >> 3);
  const int by = sw / nbx, bx = sw - by * nbx;
  const int row0 = by * 128, col0 = bx * BN_;
  const int NT = K / 64;

  // stage unit u (0..UNITS-1) of K-tile t: u 0-1 = A halves, u 2.. = B quarters/thirds
  auto stage = [&](int t, int u) {
    bf16* slot = LDS + (t % 3) * SLOT_E;
    if (u < 2) {
      const int fc = u*512 + tid;                 // 0..1023
      const int r = fc >> 3, s = fc & 7;
      const int gs = s ^ (r & 7);
      gload_lds16(Amat + (size_t)(row0 + r)*K + t*64 + gs*8,
                  slot + (size_t)fc*8 - (size_t)l*8);   // wave-uniform base + lane*16
    } else {
      const int fc = (u-2)*512 + tid;             // 0..NFRAG*512-1
      const int r = fc >> 3, s = fc & 7;
      const int gs = s ^ (r & 7);
      gload_lds16(Bt + (size_t)(col0 + r)*K + t*64 + gs*8,
                  slot + 8192 + (size_t)fc*8 - (size_t)l*8);
    }
  };

  f32x4 acc[4][NFRAG] = {};

  // prologue: stage tiles 0 and 1, wait for tile 0
#pragma unroll
  for (int u = 0; u < UNITS; ++u) stage(0, u);
#pragma unroll
  for (int u = 0; u < UNITS; ++u) stage(1, u);
  if constexpr (UNITS == 5) asm volatile("s_waitcnt vmcnt(5)" ::: "memory");
  else                      asm volatile("s_waitcnt vmcnt(6)" ::: "memory");
  __builtin_amdgcn_s_barrier();

  for (int t = 0; t < NT; ++t) {
    const bf16* slot = LDS + (t % 3) * SLOT_E;
    const bool pre = (t + 2 < NT);

    // ---- phase 0 (k-step 0) ----
    bf16x8 af[4], bfr[NFRAG];
#pragma unroll
    for (int m = 0; m < 4; ++m) {
      const int r = wm*64 + m*16 + lr;
      af[m] = *(const bf16x8*)(slot + r*64 + (hi ^ (r & 7))*8);
    }
#pragma unroll
    for (int n = 0; n < NFRAG; ++n) {
      const int r = wn*WN + n*16 + lr;
      bfr[n] = *(const bf16x8*)(slot + 8192 + r*64 + (hi ^ (r & 7))*8);
    }
    if (pre) {
      stage(t+2, 0); stage(t+2, 1); stage(t+2, 2);
      if constexpr (UNITS == 6) stage(t+2, 3);
    }
    __builtin_amdgcn_s_barrier();
    asm volatile("s_waitcnt lgkmcnt(0)" ::: "memory");
    __builtin_amdgcn_sched_barrier(0);
    __builtin_amdgcn_s_setprio(1);
#pragma unroll
    for (int m = 0; m < 4; ++m)
#pragma unroll
      for (int n = 0; n < NFRAG; ++n)
        acc[m][n] = __builtin_amdgcn_mfma_f32_16x16x32_bf16(af[m], bfr[n], acc[m][n], 0, 0, 0);
    __builtin_amdgcn_s_setprio(0);
    __builtin_amdgcn_s_barrier();

    // ---- phase 1 (k-step 1) ----
#pragma unroll
    for (int m = 0; m < 4; ++m) {
      const int r = wm*64 + m*16 + lr;
      af[m] = *(const bf16x8*)(slot + r*64 + ((4 + hi) ^ (r & 7))*8);
    }
#pragma unroll
    for (int n = 0; n < NFRAG; ++n) {
      const int r = wn*WN + n*16 + lr;
      bfr[n] = *(const bf16x8*)(slot + 8192 + r*64 + ((4 + hi) ^ (r & 7))*8);
    }
    if (pre) {
      if constexpr (UNITS == 5) { stage(t+2, 3); stage(t+2, 4); }
      else                      { stage(t+2, 4); stage(t+2, 5); }
    }
    __builtin_amdgcn_s_barrier();
    asm volatile("s_waitcnt lgkmcnt(0)" ::: "memory");
    __builtin_amdgcn_sched_barrier(0);
    __builtin_amdgcn_s_setprio(1);
#pragma unroll
    for (int m = 0; m < 4; ++m)
#pragma unroll
      for (int n = 0; n < NFRAG; ++n)
        acc[m][n] = __builtin_amdgcn_mfma_f32_16x16x32_bf16(af[m], bfr[n], acc[m][n], 0, 0, 0);
    __builtin_amdgcn_s_setprio(0);

    // ---- K-tile boundary: tile t+1 must have landed ----
    if (t < NT - 1) {
      if (pre) {
        if constexpr (UNITS == 5) asm volatile("s_waitcnt vmcnt(5)" ::: "memory");
        else                      asm volatile("s_waitcnt vmcnt(6)" ::: "memory");
      } else {
        asm volatile("s_waitcnt vmcnt(0)" ::: "memory");
      }
      __builtin_amdgcn_s_barrier();
    }
  }

  // ---- epilogue ----
#pragma unroll
  for (int m = 0; m < 4; ++m) {
#pragma unroll
    for (int n = 0; n < NFRAG; ++n) {
#pragma unroll
      for (int i = 0; i < 4; ++i) {
        const int row = row0 + wm*64 + m*16 + hi*4 + i;
        const int col = col0 + wn*WN + n*16 + lr;
        float v = acc[m][n][i] + bias[col];
        if constexpr (EPI == 1) {
          v += resF[(size_t)row*N + col];
          outF[(size_t)row*N + col] = v;
        } else if constexpr (EPI == 2) {
          v = 0.5f * v * (1.0f + erff(v * 0.7071067811865475f));
          outB[(size_t)row*N + col] = (bf16)v;
        } else if constexpr (EPI == 3) {
          v += (float)resB[(size_t)row*N + col];
          outF[(size_t)row*N + col] = v;
        } else {
          const int b = row >> 9, s = row & 511;
          const int which = col / H_;
          const int hcol = col - which * H_;
          const int h = hcol >> 6, d = hcol & 63;
          const size_t bh = (size_t)b * NH_ + h;
          if (which == 0)      outQ[(bh*S_ + s)*HD_ + d] = (bf16)v;
          else if (which == 1) outK[(bh*S_ + s)*HD_ + d] = (bf16)v;
          else                 outVT[(bh*HD_ + d)*S_ + s] = (bf16)v;
        }
      }
    }
  }
}

// ---------------- fused attention: scores -> softmax -> P (d_out) -> PV -> AO -------
__global__ __launch_bounds__(256) void k_attn_fused(
    const bf16* __restrict__ Qm, const bf16* __restrict__ Km, const bf16* __restrict__ VT,
    const unsigned char* __restrict__ mask, float* __restrict__ P, bf16* __restrict__ AO)
{
  __shared__ __align__(16) bf16 KVs[512*64];  // K rows, later reused for V^T (64x512)
  __shared__ __align__(16) bf16 Qs[64*64];
  const int tid = threadIdx.x, w = tid >> 6, l = tid & 63;
  const int lr = l & 15, hi = l >> 4;
  const int bh = blockIdx.x, qt = blockIdx.y;
  const int b = bh / NH_, h = bh - b * NH_;
  const int swz = (lr & 7) << 4;

  const bf16* Kg = Km + (size_t)bh * S_ * HD_;
  const bf16* Qg = Qm + (size_t)bh * S_ * HD_ + (size_t)qt * 64 * HD_;
#pragma unroll
  for (int rnd = 0; rnd < 16; ++rnd) {
    const int c = rnd*256 + tid;
    const int row = c >> 3, col16 = (c & 7) ^ (row & 7);
    gload_lds16(Kg + row*HD_ + col16*8, KVs + (rnd*4 + w)*512);
  }
#pragma unroll
  for (int rnd = 0; rnd < 2; ++rnd) {
    const int c = rnd*256 + tid;
    const int row = c >> 3, col16 = (c & 7) ^ (row & 7);
    gload_lds16(Qg + row*HD_ + col16*8, Qs + (rnd*4 + w)*512);
  }
  __syncthreads();

  const char* qrow = (const char*)(Qs + (w*16 + lr)*64);
  bf16x8 qf0 = *(const bf16x8*)(qrow + ((hi*16) ^ swz));
  bf16x8 qf1 = *(const bf16x8*)(qrow + ((64 + hi*16) ^ swz));
  f32x4 acc[32];
#pragma unroll
  for (int ct = 0; ct < 32; ++ct) acc[ct] = f32x4{0.f,0.f,0.f,0.f};
#pragma unroll
  for (int ct = 0; ct < 32; ++ct) {
    const char* kb = (const char*)(KVs + (ct*16 + lr)*64);
    bf16x8 a0 = *(const bf16x8*)(kb + ((hi*16) ^ swz));
    bf16x8 a1 = *(const bf16x8*)(kb + ((64 + hi*16) ^ swz));
    acc[ct] = __builtin_amdgcn_mfma_f32_16x16x32_bf16(a0, qf0, acc[ct], 0, 0, 0);
    acc[ct] = __builtin_amdgcn_mfma_f32_16x16x32_bf16(a1, qf1, acc[ct], 0, 0, 0);
  }
  __syncthreads();

  const bf16* Vg = VT + (size_t)bh * HD_ * S_;
#pragma unroll
  for (int rnd = 0; rnd < 16; ++rnd) {
    const int c = rnd*256 + tid;
    const int row = c >> 6, col16 = (c & 63) ^ (row & 7);
    gload_lds16(Vg + row*S_ + col16*8, KVs + (rnd*4 + w)*512);
  }

  const unsigned char* mrow = mask + b * S_;
  float mx = -1e30f;
#pragma unroll
  for (int ct = 0; ct < 32; ++ct) {
    const unsigned mk4 = *(const unsigned*)(mrow + ct*16 + hi*4);
#pragma unroll
    for (int i = 0; i < 4; ++i) {
      float v = acc[ct][i] * 0.125f;
      if ((mk4 >> (8*i)) & 0xff) v = -1e30f;
      acc[ct][i] = v;
      mx = fmaxf(mx, v);
    }
  }
  mx = fmaxf(mx, __shfl_xor(mx, 16));
  mx = fmaxf(mx, __shfl_xor(mx, 32));
  float sum = 0.f;
#pragma unroll
  for (int ct = 0; ct < 32; ++ct)
#pragma unroll
    for (int i = 0; i < 4; ++i) { float e = __expf(acc[ct][i] - mx); acc[ct][i] = e; sum += e; }
  sum += __shfl_xor(sum, 16);
  sum += __shfl_xor(sum, 32);
  const float inv = 1.f / sum;

  float* prow = P + ((size_t)bh*S_ + (size_t)qt*64 + w*16 + lr) * S_;
#pragma unroll
  for (int ct = 0; ct < 32; ++ct) {
#pragma unroll
    for (int i = 0; i < 4; ++i) acc[ct][i] *= inv;
    *(f32x4*)(prow + ct*16 + hi*4) = acc[ct];
  }
  __syncthreads();

  f32x4 o[4] = {};
#pragma unroll
  for (int c = 0; c < 16; ++c) {
    bf16x8 pa;
#pragma unroll
    for (int i = 0; i < 4; ++i) { pa[i] = (bf16)acc[2*c][i]; pa[4+i] = (bf16)acc[2*c+1][i]; }
    const int cb0 = (64*c + 8*hi) ^ swz;
    const int cb1 = (64*c + 32 + 8*hi) ^ swz;
#pragma unroll
    for (int nt = 0; nt < 4; ++nt) {
      const char* vb = (const char*)(KVs + (nt*16 + lr)*512);
      bf16x4 v0 = *(const bf16x4*)(vb + cb0);
      bf16x4 v1 = *(const bf16x4*)(vb + cb1);
      bf16x8 vf = {v0[0],v0[1],v0[2],v0[3], v1[0],v1[1],v1[2],v1[3]};
      o[nt] = __builtin_amdgcn_mfma_f32_16x16x32_bf16(pa, vf, o[nt], 0, 0, 0);
    }
  }

  bf16* aorow = AO + ((size_t)(b*S_ + qt*64 + w*16))*H_ + h*HD_;
#pragma unroll
  for (int nt = 0; nt < 4; ++nt)
#pragma unroll
    for (int i = 0; i < 4; ++i)
      aorow[(size_t)(hi*4 + i)*H_ + nt*16 + lr] = (bf16)o[nt][i];
}

// ---------------- LayerNorm over H=768, one row per block ---------------------------
__global__ __launch_bounds__(256) void k_layernorm(
    const float* __restrict__ X, const float* __restrict__ g, const float* __restrict__ bta,
    float* __restrict__ outF, bf16* __restrict__ outB)
{
  const int row = blockIdx.x;
  const int tid = threadIdx.x;
  const float* x = X + (size_t)row * H_;
  float v[3]; float s = 0.f, ss = 0.f;
#pragma unroll
  for (int j = 0; j < 3; ++j) { v[j] = x[tid + j*256]; s += v[j]; ss += v[j]*v[j]; }
#pragma unroll
  for (int d = 1; d < 64; d <<= 1) { s += __shfl_xor(s, d); ss += __shfl_xor(ss, d); }
  __shared__ float red[8];
  const int w = tid >> 6, l = tid & 63;
  if (l == 0) { red[w] = s; red[4 + w] = ss; }
  __syncthreads();
  s  = red[0] + red[1] + red[2] + red[3];
  ss = red[4] + red[5] + red[6] + red[7];
  const float mean = s * (1.f / H_);
  const float var  = ss * (1.f / H_) - mean * mean;
  const float inv  = rsqrtf(var + 1e-5f);
#pragma unroll
  for (int j = 0; j < 3; ++j) {
    const int c = tid + j*256;
    const float y = (v[j] - mean) * inv * g[c] + bta[c];
    if (outF) outF[(size_t)row*H_ + c] = y;
    if (outB) outB[(size_t)row*H_ + c] = (bf16)y;
  }
}

// ---------------- fused fp32 -> bf16 conversions (5 segments, 1 kernel) -------------
#define NB0 (A_*H_/1024)      // 6144
#define NB1 (3*H_*H_/1024)    // 1728
#define NB2 (H_*H_/1024)      // 576
#define NB3 (4*H_*H_/1024)    // 2304
#define NB4 (4*H_*H_/1024)    // 2304
__global__ void k_conv_all(
    const float* __restrict__ s0, bf16* __restrict__ d0,
    const float* __restrict__ s1, bf16* __restrict__ d1,
    const float* __restrict__ s2, bf16* __restrict__ d2,
    const float* __restrict__ s3, bf16* __restrict__ d3,
    const float* __restrict__ s4, bf16* __restrict__ d4)
{
  int b = blockIdx.x;
  const float* src; bf16* dst;
  if      (b < NB0)                   { src = s0; dst = d0; }
  else if ((b -= NB0) < NB1)          { src = s1; dst = d1; }
  else if ((b -= NB1) < NB2)          { src = s2; dst = d2; }
  else if ((b -= NB2) < NB3)          { src = s3; dst = d3; }
  else    { b -= NB3;                   src = s4; dst = d4; }
  const int i = (b * 256 + threadIdx.x) * 4;
  const float4 vv = *(const float4*)(src + i);
  bf16x4 o; o[0]=(bf16)vv.x; o[1]=(bf16)vv.y; o[2]=(bf16)vv.z; o[3]=(bf16)vv.w;
  *(bf16x4*)(dst + i) = o;
}

extern "C" void kernel_launch(void* const* d_in, const int* in_sizes, int n_in,
                              void* d_out, int out_size, void* d_ws, size_t ws_size,
                              hipStream_t stream) {
  const float* x      = (const float*)d_in[0];
  const unsigned char* mask = (const unsigned char*)d_in[1];
  const float* w_qkv  = (const float*)d_in[2];
  const float* b_qkv  = (const float*)d_in[3];
  const float* w_out  = (const float*)d_in[4];
  const float* b_out  = (const float*)d_in[5];
  const float* w1     = (const float*)d_in[6];
  const float* b1     = (const float*)d_in[7];
  const float* w2     = (const float*)d_in[8];
  const float* b2     = (const float*)d_in[9];
  const float* ln1g   = (const float*)d_in[10];
  const float* ln1b   = (const float*)d_in[11];
  const float* ln2g   = (const float*)d_in[12];
  const float* ln2b   = (const float*)d_in[13];

  float* xout = (float*)d_out;                      // [8192, 768]
  float* P    = xout + (size_t)A_ * H_;             // [192, 512, 512] attn weights

  char* ws = (char*)d_ws;
  size_t off = 0;
  auto alloc = [&](size_t bytes) { char* p = ws + off; off += (bytes + 255) & ~255ull; return p; };

  bf16* xb   = (bf16*)alloc((size_t)A_*H_*2);
  bf16* wqkv = (bf16*)alloc((size_t)3*H_*H_*2);
  bf16* wo   = (bf16*)alloc((size_t)H_*H_*2);
  bf16* w1b  = (bf16*)alloc((size_t)4*H_*H_*2);
  bf16* w2b  = (bf16*)alloc((size_t)4*H_*H_*2);
  char* qreg = alloc((size_t)A_*H_*2*4);               // q | k | vt | ao
  bf16* q  = (bf16*)qreg;
  bf16* kb = q  + (size_t)A_*H_;
  bf16* vt = kb + (size_t)A_*H_;
  bf16* ao = vt + (size_t)A_*H_;
  bf16* hbuf = q;                                      // [8192,3072] alias, live after ao consumed
  float* y1  = (float*)alloc((size_t)A_*H_*4);
  bf16*  x1b = (bf16*)alloc((size_t)A_*H_*2);

  // fused conversions (one kernel)
  k_conv_all<<<NB0+NB1+NB2+NB3+NB4, 256, 0, stream>>>(
      x, xb, w_qkv, wqkv, w_out, wo, w1, w1b, w2, w2b);

  // QKV projection + scatter: M=8192, N=2304 -> 64*9=576 blocks (BN=256)
  k_gemm<0,256><<<(A_/128)*(3*H_/256), 512, 0, stream>>>(xb, wqkv, b_qkv, nullptr, nullptr,
      nullptr, nullptr, q, kb, vt, A_, 3*H_, H_);
  // fused scores + softmax (P -> d_out) + PV -> attn_out
  k_attn_fused<<<dim3(B_*NH_, S_/64), 256, 0, stream>>>(q, kb, vt, mask, P, ao);
  // out_proj + residual(x): 64*4=256 blocks (BN=192)
  k_gemm<1,192><<<(A_/128)*(H_/192), 512, 0, stream>>>(ao, wo, b_out, x, nullptr,
      y1, nullptr, nullptr, nullptr, nullptr, A_, H_, H_);
  k_layernorm<<<A_, 256, 0, stream>>>(y1, ln1g, ln1b, nullptr, x1b);
  // FFN1: 64*12=768 blocks (BN=256)
  k_gemm<2,256><<<(A_/128)*(4*H_/256), 512, 0, stream>>>(x1b, w1b, b1, nullptr, nullptr,
      nullptr, hbuf, nullptr, nullptr, nullptr, A_, 4*H_, H_);
  // FFN2 + bf16 residual(x1b): 64*4=256 blocks (BN=192), K=3072
  k_gemm<3,192><<<(A_/128)*(H_/192), 512, 0, stream>>>(hbuf, w2b, b2, nullptr, x1b,
      y1, nullptr, nullptr, nullptr, nullptr, A_, H_, 4*H_);
  k_layernorm<<<A_, 256, 0, stream>>>(y1, ln2g, ln2b, xout, nullptr);
}

// Round 5
// 313.757 us; speedup vs baseline: 1.4481x; 1.0572x over previous
//
#include <hip/hip_runtime.h>
#include <hip/hip_bf16.h>
#include <math.h>

typedef __bf16 bf16;
typedef __attribute__((ext_vector_type(8))) __bf16 bf16x8;
typedef __attribute__((ext_vector_type(4))) __bf16 bf16x4;
typedef __attribute__((ext_vector_type(4))) float f32x4;

#define B_  16
#define S_  512
#define H_  768
#define NH_ 12
#define HD_ 64
#define A_  (B_*S_)   // 8192 token rows

// async global->LDS, 16B per lane; LDS dest = wave-uniform base + lane*16
__device__ __forceinline__ void gload_lds16(const void* g, void* l) {
  __builtin_amdgcn_global_load_lds((const __attribute__((address_space(1))) void*)g,
                                   (__attribute__((address_space(3))) void*)l, 16, 0, 0);
}

// =====================================================================================
// Phase-pipelined GEMM: C[M,N] = A[M,K] @ Bt[N,K]^T (+bias, epilogues)
// BM=128, BN_ in {192,256}, BK=64. 512 threads = 8 waves (2M x 4N).
// LDS: 3 slots x (A[128][64] + B[BN_][64]) bf16, triple-buffered K-tiles.
// Stage of tile t+2 issued during tile t into the slot tile t-1 vacated at its trailing
// barrier. Boundary: s_waitcnt vmcnt(UNITS) + s_barrier => tile t+1 landed.
// XOR swizzle: LDS col-slot = global-slot ^ (row&7), both sides; 2-way conflicts (free).
// EPI 0: QKV scatter; EPI 1: +resF fp32; EPI 2: gelu->bf16; EPI 3: +resB bf16
// =====================================================================================
template<int EPI, int BN_>
__global__ __launch_bounds__(512, 2) void k_gemm(
    const bf16* __restrict__ Amat, const bf16* __restrict__ Bt,
    const float* __restrict__ bias, const float* __restrict__ resF,
    const bf16* __restrict__ resB,
    float* __restrict__ outF, bf16* __restrict__ outB,
    bf16* __restrict__ outQ, bf16* __restrict__ outK, bf16* __restrict__ outVT,
    int M, int N, int K)
{
  constexpr int NFRAG  = BN_ / 64;        // 3 or 4
  constexpr int UNITS  = 2 + NFRAG;       // 8KB stage units per K-tile
  constexpr int SLOT_E = 8192 + BN_ * 64; // elems per LDS slot
  constexpr int WN     = BN_ / 4;         // per-wave N extent
  __shared__ __align__(16) bf16 LDS[3 * SLOT_E];
  const int tid = threadIdx.x;
  const int w = tid >> 6, l = tid & 63;
  const int lr = l & 15, hi = l >> 4;
  const int wm = w >> 2, wn = w & 3;

  // XCD-aware bijective swizzle (gridDim.x % 8 == 0 for all our launches)
  const int nbx = N / BN_;
  const int cpx = gridDim.x >> 3;
  const int sw  = (blockIdx.x & 7) * cpx + (blockIdx.x >> 3);
  const int by = sw / nbx, bx = sw - by * nbx;
  const int row0 = by * 128, col0 = bx * BN_;
  const int NT = K / 64;

  auto stage = [&](int t, int u) {
    bf16* slot = LDS + (t % 3) * SLOT_E;
    if (u < 2) {
      const int fc = u*512 + tid;
      const int r = fc >> 3, s = fc & 7;
      const int gs = s ^ (r & 7);
      gload_lds16(Amat + (size_t)(row0 + r)*K + t*64 + gs*8,
                  slot + (size_t)fc*8 - (size_t)l*8);
    } else {
      const int fc = (u-2)*512 + tid;
      const int r = fc >> 3, s = fc & 7;
      const int gs = s ^ (r & 7);
      gload_lds16(Bt + (size_t)(col0 + r)*K + t*64 + gs*8,
                  slot + 8192 + (size_t)fc*8 - (size_t)l*8);
    }
  };

  f32x4 acc[4][NFRAG] = {};

#pragma unroll
  for (int u = 0; u < UNITS; ++u) stage(0, u);
#pragma unroll
  for (int u = 0; u < UNITS; ++u) stage(1, u);
  if constexpr (UNITS == 5) asm volatile("s_waitcnt vmcnt(5)" ::: "memory");
  else                      asm volatile("s_waitcnt vmcnt(6)" ::: "memory");
  __builtin_amdgcn_s_barrier();

  for (int t = 0; t < NT; ++t) {
    const bf16* slot = LDS + (t % 3) * SLOT_E;
    const bool pre = (t + 2 < NT);

    // ---- phase 0 ----
    bf16x8 af[4], bfr[NFRAG];
#pragma unroll
    for (int m = 0; m < 4; ++m) {
      const int r = wm*64 + m*16 + lr;
      af[m] = *(const bf16x8*)(slot + r*64 + (hi ^ (r & 7))*8);
    }
#pragma unroll
    for (int n = 0; n < NFRAG; ++n) {
      const int r = wn*WN + n*16 + lr;
      bfr[n] = *(const bf16x8*)(slot + 8192 + r*64 + (hi ^ (r & 7))*8);
    }
    if (pre) {
      stage(t+2, 0); stage(t+2, 1); stage(t+2, 2);
      if constexpr (UNITS == 6) stage(t+2, 3);
    }
    __builtin_amdgcn_s_barrier();
    asm volatile("s_waitcnt lgkmcnt(0)" ::: "memory");
    __builtin_amdgcn_sched_barrier(0);
    __builtin_amdgcn_s_setprio(1);
#pragma unroll
    for (int m = 0; m < 4; ++m)
#pragma unroll
      for (int n = 0; n < NFRAG; ++n)
        acc[m][n] = __builtin_amdgcn_mfma_f32_16x16x32_bf16(af[m], bfr[n], acc[m][n], 0, 0, 0);
    __builtin_amdgcn_s_setprio(0);
    __builtin_amdgcn_s_barrier();

    // ---- phase 1 ----
#pragma unroll
    for (int m = 0; m < 4; ++m) {
      const int r = wm*64 + m*16 + lr;
      af[m] = *(const bf16x8*)(slot + r*64 + ((4 + hi) ^ (r & 7))*8);
    }
#pragma unroll
    for (int n = 0; n < NFRAG; ++n) {
      const int r = wn*WN + n*16 + lr;
      bfr[n] = *(const bf16x8*)(slot + 8192 + r*64 + ((4 + hi) ^ (r & 7))*8);
    }
    if (pre) {
      if constexpr (UNITS == 5) { stage(t+2, 3); stage(t+2, 4); }
      else                      { stage(t+2, 4); stage(t+2, 5); }
    }
    __builtin_amdgcn_s_barrier();
    asm volatile("s_waitcnt lgkmcnt(0)" ::: "memory");
    __builtin_amdgcn_sched_barrier(0);
    __builtin_amdgcn_s_setprio(1);
#pragma unroll
    for (int m = 0; m < 4; ++m)
#pragma unroll
      for (int n = 0; n < NFRAG; ++n)
        acc[m][n] = __builtin_amdgcn_mfma_f32_16x16x32_bf16(af[m], bfr[n], acc[m][n], 0, 0, 0);
    __builtin_amdgcn_s_setprio(0);

    if (t < NT - 1) {
      if (pre) {
        if constexpr (UNITS == 5) asm volatile("s_waitcnt vmcnt(5)" ::: "memory");
        else                      asm volatile("s_waitcnt vmcnt(6)" ::: "memory");
      } else {
        asm volatile("s_waitcnt vmcnt(0)" ::: "memory");
      }
      __builtin_amdgcn_s_barrier();
    }
  }

  // ---- epilogue ----
#pragma unroll
  for (int m = 0; m < 4; ++m) {
#pragma unroll
    for (int n = 0; n < NFRAG; ++n) {
#pragma unroll
      for (int i = 0; i < 4; ++i) {
        const int row = row0 + wm*64 + m*16 + hi*4 + i;
        const int col = col0 + wn*WN + n*16 + lr;
        float v = acc[m][n][i] + bias[col];
        if constexpr (EPI == 1) {
          v += resF[(size_t)row*N + col];
          outF[(size_t)row*N + col] = v;
        } else if constexpr (EPI == 2) {
          v = 0.5f * v * (1.0f + erff(v * 0.7071067811865475f));
          outB[(size_t)row*N + col] = (bf16)v;
        } else if constexpr (EPI == 3) {
          v += (float)resB[(size_t)row*N + col];
          outF[(size_t)row*N + col] = v;
        } else {
          const int b = row >> 9, s = row & 511;
          const int which = col / H_;
          const int hcol = col - which * H_;
          const int h = hcol >> 6, d = hcol & 63;
          const size_t bh = (size_t)b * NH_ + h;
          if (which == 0)      outQ[(bh*S_ + s)*HD_ + d] = (bf16)v;
          else if (which == 1) outK[(bh*S_ + s)*HD_ + d] = (bf16)v;
          else                 outVT[(bh*HD_ + d)*S_ + s] = (bf16)v;
        }
      }
    }
  }
}

// ---------------- fused attention: scores -> softmax -> P (d_out) -> PV -> AO -------
// 1536 blocks, XCD-grouped: all 8 qt-blocks of one head run on one XCD so K/V are
// fetched from HBM once and served from that XCD's L2 for the other 7 blocks.
__global__ __launch_bounds__(256) void k_attn_fused(
    const bf16* __restrict__ Qm, const bf16* __restrict__ Km, const bf16* __restrict__ VT,
    const unsigned char* __restrict__ mask, float* __restrict__ P, bf16* __restrict__ AO)
{
  __shared__ __align__(16) bf16 KVs[512*64];  // K rows, later reused for V^T (64x512)
  __shared__ __align__(16) bf16 Qs[64*64];
  const int tid = threadIdx.x, w = tid >> 6, l = tid & 63;
  const int lr = l & 15, hi = l >> 4;
  // XCD-grouped decode: XCD x (= blockIdx.x%8) handles sw in [x*192,(x+1)*192):
  // bh in [x*24,(x+1)*24), qt fastest -> same-head blocks co-resident on one XCD.
  const int cpx = gridDim.x >> 3;                       // 192
  const int sw  = (blockIdx.x & 7) * cpx + (blockIdx.x >> 3);
  const int bh = sw >> 3, qt = sw & 7;
  const int b = bh / NH_, h = bh - b * NH_;
  const int swz = (lr & 7) << 4;

  const bf16* Kg = Km + (size_t)bh * S_ * HD_;
  const bf16* Qg = Qm + (size_t)bh * S_ * HD_ + (size_t)qt * 64 * HD_;
#pragma unroll
  for (int rnd = 0; rnd < 16; ++rnd) {
    const int c = rnd*256 + tid;
    const int row = c >> 3, col16 = (c & 7) ^ (row & 7);
    gload_lds16(Kg + row*HD_ + col16*8, KVs + (rnd*4 + w)*512);
  }
#pragma unroll
  for (int rnd = 0; rnd < 2; ++rnd) {
    const int c = rnd*256 + tid;
    const int row = c >> 3, col16 = (c & 7) ^ (row & 7);
    gload_lds16(Qg + row*HD_ + col16*8, Qs + (rnd*4 + w)*512);
  }
  __syncthreads();

  const char* qrow = (const char*)(Qs + (w*16 + lr)*64);
  bf16x8 qf0 = *(const bf16x8*)(qrow + ((hi*16) ^ swz));
  bf16x8 qf1 = *(const bf16x8*)(qrow + ((64 + hi*16) ^ swz));
  f32x4 acc[32];
#pragma unroll
  for (int ct = 0; ct < 32; ++ct) acc[ct] = f32x4{0.f,0.f,0.f,0.f};
#pragma unroll
  for (int ct = 0; ct < 32; ++ct) {
    const char* kb = (const char*)(KVs + (ct*16 + lr)*64);
    bf16x8 a0 = *(const bf16x8*)(kb + ((hi*16) ^ swz));
    bf16x8 a1 = *(const bf16x8*)(kb + ((64 + hi*16) ^ swz));
    acc[ct] = __builtin_amdgcn_mfma_f32_16x16x32_bf16(a0, qf0, acc[ct], 0, 0, 0);
    acc[ct] = __builtin_amdgcn_mfma_f32_16x16x32_bf16(a1, qf1, acc[ct], 0, 0, 0);
  }
  __syncthreads();

  const bf16* Vg = VT + (size_t)bh * HD_ * S_;
#pragma unroll
  for (int rnd = 0; rnd < 16; ++rnd) {
    const int c = rnd*256 + tid;
    const int row = c >> 6, col16 = (c & 63) ^ (row & 7);
    gload_lds16(Vg + row*S_ + col16*8, KVs + (rnd*4 + w)*512);
  }

  const unsigned char* mrow = mask + b * S_;
  float mx = -1e30f;
#pragma unroll
  for (int ct = 0; ct < 32; ++ct) {
    const unsigned mk4 = *(const unsigned*)(mrow + ct*16 + hi*4);
#pragma unroll
    for (int i = 0; i < 4; ++i) {
      float v = acc[ct][i] * 0.125f;
      if ((mk4 >> (8*i)) & 0xff) v = -1e30f;
      acc[ct][i] = v;
      mx = fmaxf(mx, v);
    }
  }
  mx = fmaxf(mx, __shfl_xor(mx, 16));
  mx = fmaxf(mx, __shfl_xor(mx, 32));
  float sum = 0.f;
#pragma unroll
  for (int ct = 0; ct < 32; ++ct)
#pragma unroll
    for (int i = 0; i < 4; ++i) { float e = __expf(acc[ct][i] - mx); acc[ct][i] = e; sum += e; }
  sum += __shfl_xor(sum, 16);
  sum += __shfl_xor(sum, 32);
  const float inv = 1.f / sum;

  float* prow = P + ((size_t)bh*S_ + (size_t)qt*64 + w*16 + lr) * S_;
#pragma unroll
  for (int ct = 0; ct < 32; ++ct) {
#pragma unroll
    for (int i = 0; i < 4; ++i) acc[ct][i] *= inv;
    *(f32x4*)(prow + ct*16 + hi*4) = acc[ct];
  }
  __syncthreads();

  f32x4 o[4] = {};
#pragma unroll
  for (int c = 0; c < 16; ++c) {
    bf16x8 pa;
#pragma unroll
    for (int i = 0; i < 4; ++i) { pa[i] = (bf16)acc[2*c][i]; pa[4+i] = (bf16)acc[2*c+1][i]; }
    const int cb0 = (64*c + 8*hi) ^ swz;
    const int cb1 = (64*c + 32 + 8*hi) ^ swz;
#pragma unroll
    for (int nt = 0; nt < 4; ++nt) {
      const char* vb = (const char*)(KVs + (nt*16 + lr)*512);
      bf16x4 v0 = *(const bf16x4*)(vb + cb0);
      bf16x4 v1 = *(const bf16x4*)(vb + cb1);
      bf16x8 vf = {v0[0],v0[1],v0[2],v0[3], v1[0],v1[1],v1[2],v1[3]};
      o[nt] = __builtin_amdgcn_mfma_f32_16x16x32_bf16(pa, vf, o[nt], 0, 0, 0);
    }
  }

  bf16* aorow = AO + ((size_t)(b*S_ + qt*64 + w*16))*H_ + h*HD_;
#pragma unroll
  for (int nt = 0; nt < 4; ++nt)
#pragma unroll
    for (int i = 0; i < 4; ++i)
      aorow[(size_t)(hi*4 + i)*H_ + nt*16 + lr] = (bf16)o[nt][i];
}

// ---------------- LayerNorm over H=768: one wave per row, 4 rows/block ---------------
__global__ __launch_bounds__(256) void k_layernorm(
    const float* __restrict__ X, const float* __restrict__ g, const float* __restrict__ bta,
    float* __restrict__ outF, bf16* __restrict__ outB)
{
  const int w = threadIdx.x >> 6, l = threadIdx.x & 63;
  const int row = blockIdx.x * 4 + w;
  const float* x = X + (size_t)row * H_;
  float4 v[3]; float s = 0.f, ss = 0.f;
#pragma unroll
  for (int j = 0; j < 3; ++j) {
    v[j] = *(const float4*)(x + l*4 + j*256);
    s  += v[j].x + v[j].y + v[j].z + v[j].w;
    ss += v[j].x*v[j].x + v[j].y*v[j].y + v[j].z*v[j].z + v[j].w*v[j].w;
  }
#pragma unroll
  for (int d = 1; d < 64; d <<= 1) { s += __shfl_xor(s, d); ss += __shfl_xor(ss, d); }
  const float mean = s * (1.f / H_);
  const float var  = ss * (1.f / H_) - mean * mean;
  const float inv  = rsqrtf(var + 1e-5f);
#pragma unroll
  for (int j = 0; j < 3; ++j) {
    const int c = l*4 + j*256;
    const float4 gv = *(const float4*)(g + c);
    const float4 bv = *(const float4*)(bta + c);
    float4 y;
    y.x = (v[j].x - mean)*inv*gv.x + bv.x;
    y.y = (v[j].y - mean)*inv*gv.y + bv.y;
    y.z = (v[j].z - mean)*inv*gv.z + bv.z;
    y.w = (v[j].w - mean)*inv*gv.w + bv.w;
    if (outF) *(float4*)(outF + (size_t)row*H_ + c) = y;
    if (outB) {
      bf16x4 o; o[0]=(bf16)y.x; o[1]=(bf16)y.y; o[2]=(bf16)y.z; o[3]=(bf16)y.w;
      *(bf16x4*)(outB + (size_t)row*H_ + c) = o;
    }
  }
}

// ---------------- fused fp32 -> bf16 conversions (5 segments, 1 kernel) -------------
#define NB0 (A_*H_/1024)      // 6144
#define NB1 (3*H_*H_/1024)    // 1728
#define NB2 (H_*H_/1024)      // 576
#define NB3 (4*H_*H_/1024)    // 2304
#define NB4 (4*H_*H_/1024)    // 2304
__global__ void k_conv_all(
    const float* __restrict__ s0, bf16* __restrict__ d0,
    const float* __restrict__ s1, bf16* __restrict__ d1,
    const float* __restrict__ s2, bf16* __restrict__ d2,
    const float* __restrict__ s3, bf16* __restrict__ d3,
    const float* __restrict__ s4, bf16* __restrict__ d4)
{
  int b = blockIdx.x;
  const float* src; bf16* dst;
  if      (b < NB0)                   { src = s0; dst = d0; }
  else if ((b -= NB0) < NB1)          { src = s1; dst = d1; }
  else if ((b -= NB1) < NB2)          { src = s2; dst = d2; }
  else if ((b -= NB2) < NB3)          { src = s3; dst = d3; }
  else    { b -= NB3;                   src = s4; dst = d4; }
  const int i = (b * 256 + threadIdx.x) * 4;
  const float4 vv = *(const float4*)(src + i);
  bf16x4 o; o[0]=(bf16)vv.x; o[1]=(bf16)vv.y; o[2]=(bf16)vv.z; o[3]=(bf16)vv.w;
  *(bf16x4*)(dst + i) = o;
}

extern "C" void kernel_launch(void* const* d_in, const int* in_sizes, int n_in,
                              void* d_out, int out_size, void* d_ws, size_t ws_size,
                              hipStream_t stream) {
  const float* x      = (const float*)d_in[0];
  const unsigned char* mask = (const unsigned char*)d_in[1];
  const float* w_qkv  = (const float*)d_in[2];
  const float* b_qkv  = (const float*)d_in[3];
  const float* w_out  = (const float*)d_in[4];
  const float* b_out  = (const float*)d_in[5];
  const float* w1     = (const float*)d_in[6];
  const float* b1     = (const float*)d_in[7];
  const float* w2     = (const float*)d_in[8];
  const float* b2     = (const float*)d_in[9];
  const float* ln1g   = (const float*)d_in[10];
  const float* ln1b   = (const float*)d_in[11];
  const float* ln2g   = (const float*)d_in[12];
  const float* ln2b   = (const float*)d_in[13];

  float* xout = (float*)d_out;                      // [8192, 768]
  float* P    = xout + (size_t)A_ * H_;             // [192, 512, 512] attn weights

  char* ws = (char*)d_ws;
  size_t off = 0;
  auto alloc = [&](size_t bytes) { char* p = ws + off; off += (bytes + 255) & ~255ull; return p; };

  bf16* xb   = (bf16*)alloc((size_t)A_*H_*2);
  bf16* wqkv = (bf16*)alloc((size_t)3*H_*H_*2);
  bf16* wo   = (bf16*)alloc((size_t)H_*H_*2);
  bf16* w1b  = (bf16*)alloc((size_t)4*H_*H_*2);
  bf16* w2b  = (bf16*)alloc((size_t)4*H_*H_*2);
  char* qreg = alloc((size_t)A_*H_*2*4);               // q | k | vt | ao
  bf16* q  = (bf16*)qreg;
  bf16* kb = q  + (size_t)A_*H_;
  bf16* vt = kb + (size_t)A_*H_;
  bf16* ao = vt + (size_t)A_*H_;
  bf16* hbuf = q;                                      // [8192,3072] alias, live after ao consumed
  float* y1  = (float*)alloc((size_t)A_*H_*4);
  bf16*  x1b = (bf16*)alloc((size_t)A_*H_*2);

  // fused conversions (one kernel)
  k_conv_all<<<NB0+NB1+NB2+NB3+NB4, 256, 0, stream>>>(
      x, xb, w_qkv, wqkv, w_out, wo, w1, w1b, w2, w2b);

  // QKV projection + scatter: M=8192, N=2304 -> 64*12=768 blocks (BN=192, 3 full rounds)
  k_gemm<0,192><<<(A_/128)*(3*H_/192), 512, 0, stream>>>(xb, wqkv, b_qkv, nullptr, nullptr,
      nullptr, nullptr, q, kb, vt, A_, 3*H_, H_);
  // fused scores + softmax (P -> d_out) + PV -> attn_out (XCD-grouped)
  k_attn_fused<<<B_*NH_*8, 256, 0, stream>>>(q, kb, vt, mask, P, ao);
  // out_proj + residual(x): 64*4=256 blocks (BN=192)
  k_gemm<1,192><<<(A_/128)*(H_/192), 512, 0, stream>>>(ao, wo, b_out, x, nullptr,
      y1, nullptr, nullptr, nullptr, nullptr, A_, H_, H_);
  k_layernorm<<<A_/4, 256, 0, stream>>>(y1, ln1g, ln1b, nullptr, x1b);
  // FFN1: 64*12=768 blocks (BN=256)
  k_gemm<2,256><<<(A_/128)*(4*H_/256), 512, 0, stream>>>(x1b, w1b, b1, nullptr, nullptr,
      nullptr, hbuf, nullptr, nullptr, nullptr, A_, 4*H_, H_);
  // FFN2 + bf16 residual(x1b): 64*4=256 blocks (BN=192), K=3072
  k_gemm<3,192><<<(A_/128)*(H_/192), 512, 0, stream>>>(hbuf, w2b, b2, nullptr, x1b,
      y1, nullptr, nullptr, nullptr, nullptr, A_, H_, 4*H_);
  k_layernorm<<<A_/4, 256, 0, stream>>>(y1, ln2g, ln2b, xout, nullptr);
}